// Round 14
// baseline (191.204 us; speedup 1.0000x reference)
//
#include <hip/hip_runtime.h>
#include <math.h>

#define BN_EPS 1e-5f

typedef __attribute__((ext_vector_type(8))) short short8v;   // 8 x bf16 bits
typedef __attribute__((ext_vector_type(8))) unsigned short ushort8v;
typedef __attribute__((ext_vector_type(4))) float f32x4;

__device__ __forceinline__ unsigned short f2b(float f) {
    unsigned int u = __float_as_uint(f);
    return (unsigned short)((u + 0x7FFFu + ((u >> 16) & 1u)) >> 16);
}
__device__ __forceinline__ float b2f(unsigned short h) {
    return __uint_as_float(((unsigned int)h) << 16);
}

// async global->LDS, 16B per lane. dest wave-uniform base; HW writes
// base + lane*16. Global source IS per-lane.
typedef __attribute__((address_space(1))) const unsigned int gas_uint;
typedef __attribute__((address_space(3))) unsigned int las_uint;
__device__ __forceinline__ void gload16(const void* g, void* l) {
    __builtin_amdgcn_global_load_lds((gas_uint*)g, (las_uint*)l, 16, 0, 0);
}

#define VMCNT2()  asm volatile("s_waitcnt vmcnt(2)"  ::: "memory")
#define VMCNT3()  asm volatile("s_waitcnt vmcnt(3)"  ::: "memory")
#define VMCNT4()  asm volatile("s_waitcnt vmcnt(4)"  ::: "memory")
#define VMCNT6()  asm volatile("s_waitcnt vmcnt(6)"  ::: "memory")
#define VMCNT8()  asm volatile("s_waitcnt vmcnt(8)"  ::: "memory")
#define VMCNT0()  asm volatile("s_waitcnt vmcnt(0)"  ::: "memory")
#define LGKM0()   asm volatile("s_waitcnt lgkmcnt(0)" ::: "memory")
#define SBAR()    __builtin_amdgcn_s_barrier()
#define SCHED0()  __builtin_amdgcn_sched_barrier(0)

// ---------------------------------------------------------------------------
// prep_all: weight/proto conversions + conv transpose + opad zero.
// Segments in 8-elem chunks:
//   [0,49152) w0   [49152,57344) wr   [57344,73728) wp   [73728,106496) wf
//   [106496,188416) protos
//   [188416,225280) conv weight transpose -> wt[br][tap][oc][ic]
//   [225280,557056) zero opad
// ---------------------------------------------------------------------------
__global__ __launch_bounds__(256) void prep_all(
    const float* __restrict__ w0,  const float* __restrict__ wr,
    const float* __restrict__ wp,  const float* __restrict__ wf,
    const float* __restrict__ prot,
    const float* __restrict__ wl,  const float* __restrict__ wg,
    unsigned short* __restrict__ w0_o, unsigned short* __restrict__ wr_o,
    unsigned short* __restrict__ wp_o, unsigned short* __restrict__ wf_o,
    unsigned short* __restrict__ prot_o,
    unsigned short* __restrict__ wt_o, unsigned short* __restrict__ opad)
{
    int i = blockIdx.x * 256 + threadIdx.x;
    if (i >= 557056) return;
    if (i >= 225280) {                // zero opad
        ushort8v z;
#pragma unroll
        for (int k = 0; k < 8; ++k) z[k] = 0;
        *(ushort8v*)(opad + (size_t)(i - 225280) * 8) = z;
        return;
    }
    if (i >= 188416) {                // conv weight transpose (gather)
        int e0 = (i - 188416) * 8;
        ushort8v u;
#pragma unroll
        for (int q = 0; q < 8; ++q) {
            int e = e0 + q;
            int br = e >= 147456;
            int j  = e - br * 147456;
            int tap = j >> 14, oc = (j >> 7) & 127, ic = j & 127;
            const float* src = br ? wg : wl;
            u[q] = f2b(src[((oc << 7) + ic) * 9 + tap]);
        }
        *(ushort8v*)(wt_o + (size_t)e0) = u;
        return;
    }
    const float* src; unsigned short* dst; int off;
    if      (i <  49152) { src = w0;   dst = w0_o;   off = i; }
    else if (i <  57344) { src = wr;   dst = wr_o;   off = i - 49152; }
    else if (i <  73728) { src = wp;   dst = wp_o;   off = i - 57344; }
    else if (i < 106496) { src = wf;   dst = wf_o;   off = i - 73728; }
    else                 { src = prot; dst = prot_o; off = i - 106496; }
    const float4* p = (const float4*)(src + (size_t)off * 8);
    float4 a = p[0], b = p[1];
    ushort8v r;
    r[0] = f2b(a.x); r[1] = f2b(a.y); r[2] = f2b(a.z); r[3] = f2b(a.w);
    r[4] = f2b(b.x); r[5] = f2b(b.y); r[6] = f2b(b.z); r[7] = f2b(b.w);
    *(ushort8v*)(dst + (size_t)off * 8) = r;
}

// ---------------------------------------------------------------------------
// Adapter GEMM, fp32 A converted in-kernel, DEPTH-2 pipeline on BOTH
// operands: A reg-staged double-buffer (arA/arB, static indices via 2x
// unrolled loop), B via 3-buffer gload_lds ring. Per step ks:
//   issue A(ks+2)->NXT, B(ks+2)->ring; vmcnt(8) waits A(ks+1) (issued a
//   full step ago -> no stall); WRITEA; MFMA; vmcnt(6) waits B(ks+1); bar.
// Queue at wait points: A(k+1)4, B(k+1)2, A(k+2)4, B(k+2)2.
// nK must be even (adapter: K=768 -> nK=24).
// ---------------------------------------------------------------------------
__global__ __launch_bounds__(256, 3) void mfma_gemm_f32a(
    const float* __restrict__ A, int lda,
    const unsigned short* __restrict__ Wt, int ldw,
    unsigned short* __restrict__ outp, int ldc, int Kdim,
    const float* __restrict__ bng, const float* __restrict__ bnb,
    const float* __restrict__ bnm, const float* __restrict__ bnv)
{
    __shared__ short8v Asta[2][512];
    __shared__ short8v Bsta[3][512];
    const int t  = threadIdx.x;
    const int l  = t & 63, wv = t >> 6;
    const int wm = wv >> 1, wn = wv & 1;
    const int m0 = blockIdx.x << 7, n0 = blockIdx.y << 7;

    const int r0  = t & 127;
    const int kb0 = t >> 7;

    const float*          Apf = A  + (size_t)(m0 + r0) * lda + kb0 * 8;
    const unsigned short* Bp  = Wt + (size_t)(n0 + r0) * ldw + kb0 * 8;

    f32x4 acc[4][4];
#pragma unroll
    for (int mf = 0; mf < 4; ++mf)
#pragma unroll
        for (int nf = 0; nf < 4; ++nf)
#pragma unroll
            for (int j = 0; j < 4; ++j) acc[mf][nf][j] = 0.f;

    const int arow = wm * 64 + (l & 15);
    const int brow = wn * 64 + (l & 15);
    const int kq   = l >> 4;
    const int nK   = Kdim >> 5;   // EVEN (24 for adapter)

    float4 arA[2][2], arB[2][2];

#define LOADA(AR, k0)                                     \
    do {                                                  \
        AR[0][0] = *(const float4*)(Apf + (k0));          \
        AR[0][1] = *(const float4*)(Apf + (k0) + 4);      \
        AR[1][0] = *(const float4*)(Apf + (k0) + 16);     \
        AR[1][1] = *(const float4*)(Apf + (k0) + 20);     \
    } while (0)

#define WRITEA(AR, buf)                                             \
    do {                                                            \
        _Pragma("unroll")                                           \
        for (int c_ = 0; c_ < 2; ++c_) {                            \
            ushort8v u_;                                            \
            u_[0] = f2b(AR[c_][0].x); u_[1] = f2b(AR[c_][0].y);     \
            u_[2] = f2b(AR[c_][0].z); u_[3] = f2b(AR[c_][0].w);     \
            u_[4] = f2b(AR[c_][1].x); u_[5] = f2b(AR[c_][1].y);     \
            u_[6] = f2b(AR[c_][1].z); u_[7] = f2b(AR[c_][1].w);     \
            *(ushort8v*)&Asta[buf][t + 256 * c_] = u_;              \
        }                                                           \
    } while (0)

#define STAGEB(buf, k0)                                      \
    do {                                                     \
        gload16(Bp + (k0),      &Bsta[buf][wv * 64]);        \
        gload16(Bp + (k0) + 16, &Bsta[buf][wv * 64 + 256]);  \
    } while (0)

#define MFMA_STEP(ks)                                                          \
    do {                                                                       \
        const int cA_ = (ks) & 1;                                              \
        short8v af_[4], bfv_[4];                                               \
        _Pragma("unroll")                                                      \
        for (int mf = 0; mf < 4; ++mf)                                         \
            af_[mf]  = Asta[cA_][kq * 128 + arow + mf * 16];                   \
        _Pragma("unroll")                                                      \
        for (int nf = 0; nf < 4; ++nf)                                         \
            bfv_[nf] = Bsta[(ks) % 3][kq * 128 + brow + nf * 16];              \
        _Pragma("unroll")                                                      \
        for (int mf = 0; mf < 4; ++mf)                                         \
            _Pragma("unroll")                                                  \
            for (int nf = 0; nf < 4; ++nf)                                     \
                acc[mf][nf] = __builtin_amdgcn_mfma_f32_16x16x32_bf16(         \
                    af_[mf], bfv_[nf], acc[mf][nf], 0, 0, 0);                  \
    } while (0)

    // STEP(ks, CUR=set holding tile ks+1, NXT=free set for tile ks+2)
#define STEP(ks, CUR, NXT)                                                     \
    do {                                                                       \
        const bool i2_ = (ks) + 2 < nK;                                        \
        const bool w1_ = (ks) + 1 < nK;                                        \
        if (i2_) { LOADA(NXT, ((ks) + 2) << 5); STAGEB(((ks) + 2) % 3, ((ks) + 2) << 5); } \
        if (w1_) {                                                             \
            if (i2_) VMCNT8(); else VMCNT2();   /* A(ks+1) landed */           \
            WRITEA(CUR, ((ks) + 1) & 1);                                       \
        }                                                                      \
        MFMA_STEP(ks);                                                         \
        if (w1_) {                                                             \
            if (i2_) VMCNT6(); else VMCNT0();   /* B(ks+1) landed */           \
            LGKM0(); SCHED0();                                                 \
            SBAR();                                                            \
        }                                                                      \
    } while (0)

    // prologue: tiles 0 and 1
    LOADA(arA, 0);
    STAGEB(0, 0);
    LOADA(arB, 32);
    STAGEB(1, 32);
    VMCNT8();                 // A(0) landed (B0:2, A1:4, B1:2 outstanding)
    WRITEA(arA, 0);
    VMCNT6();                 // B(0) landed (A1:4, B1:2 outstanding)
    LGKM0();
    SBAR();

    for (int ks = 0; ks < nK; ks += 2) {
        STEP(ks, arB, arA);       // even step: tile ks+1 lives in arB
        STEP(ks + 1, arA, arB);   // odd step: tile ks+2 lives in arA
    }
#undef LOADA
#undef WRITEA
#undef STAGEB
#undef MFMA_STEP
#undef STEP

    float s[4], sh[4];
    int cols[4];
#pragma unroll
    for (int nf = 0; nf < 4; ++nf) {
        int col = n0 + wn * 64 + nf * 16 + (l & 15);
        cols[nf] = col;
        float sc = bng[col] * rsqrtf(bnv[col] + BN_EPS);
        s[nf]  = sc;
        sh[nf] = bnb[col] - bnm[col] * sc;
    }
#pragma unroll
    for (int mf = 0; mf < 4; ++mf) {
#pragma unroll
        for (int j = 0; j < 4; ++j) {
            int row = m0 + wm * 64 + mf * 16 + kq * 4 + j;
#pragma unroll
            for (int nf = 0; nf < 4; ++nf) {
                float v = fmaxf(acc[mf][nf][j] * s[nf] + sh[nf], 0.f);
                outp[(size_t)row * ldc + cols[nf]] = f2b(v);
            }
        }
    }
}

// ---------------------------------------------------------------------------
// bf16 MFMA NT GEMM (R6-proven): tile 128x128, BK=32, 256 threads (4 waves),
// acc 4x4. 2-buffer LDS + counted vmcnt(4).
// EPI 1: BN+res+ReLU->bf16  2: +bias->fp32
// ---------------------------------------------------------------------------
template <int EPI>
__global__ __launch_bounds__(256, 3) void mfma_gemm(
    const unsigned short* __restrict__ A, int lda,
    const unsigned short* __restrict__ Wt, int ldw,
    void* __restrict__ outp, int ldc, int Kdim,
    const float* __restrict__ bng, const float* __restrict__ bnb,
    const float* __restrict__ bnm, const float* __restrict__ bnv,
    const unsigned short* __restrict__ res, int ldres,
    const float* __restrict__ bias)
{
    __shared__ short8v Asta[2][512];
    __shared__ short8v Bsta[2][512];
    const int t  = threadIdx.x;
    const int l  = t & 63, wv = t >> 6;
    const int wm = wv >> 1, wn = wv & 1;
    const int m0 = blockIdx.x << 7, n0 = blockIdx.y << 7;

    const int r0  = t & 127;
    const int kb0 = t >> 7;

    const unsigned short* Ap = A  + (size_t)(m0 + r0) * lda + kb0 * 8;
    const unsigned short* Bp = Wt + (size_t)(n0 + r0) * ldw + kb0 * 8;

    f32x4 acc[4][4];
#pragma unroll
    for (int mf = 0; mf < 4; ++mf)
#pragma unroll
        for (int nf = 0; nf < 4; ++nf)
#pragma unroll
            for (int j = 0; j < 4; ++j) acc[mf][nf][j] = 0.f;

    const int arow = wm * 64 + (l & 15);
    const int brow = wn * 64 + (l & 15);
    const int kq   = l >> 4;
    const int nK   = Kdim >> 5;

#define STAGE_G(buf, k0)                                     \
    do {                                                     \
        gload16(Ap + (k0),      &Asta[buf][wv * 64]);        \
        gload16(Ap + (k0) + 16, &Asta[buf][wv * 64 + 256]);  \
        gload16(Bp + (k0),      &Bsta[buf][wv * 64]);        \
        gload16(Bp + (k0) + 16, &Bsta[buf][wv * 64 + 256]);  \
    } while (0)

    STAGE_G(0, 0);
    int cur = 0;
    for (int ks = 0; ks < nK; ++ks) {
        if (ks + 1 < nK) { STAGE_G(cur ^ 1, (ks + 1) << 5); VMCNT4(); }
        else             { VMCNT0(); }
        SBAR();
        short8v af[4], bfv[4];
#pragma unroll
        for (int mf = 0; mf < 4; ++mf) af[mf]  = Asta[cur][kq * 128 + arow + mf * 16];
#pragma unroll
        for (int nf = 0; nf < 4; ++nf) bfv[nf] = Bsta[cur][kq * 128 + brow + nf * 16];
#pragma unroll
        for (int mf = 0; mf < 4; ++mf)
#pragma unroll
            for (int nf = 0; nf < 4; ++nf)
                acc[mf][nf] = __builtin_amdgcn_mfma_f32_16x16x32_bf16(
                    af[mf], bfv[nf], acc[mf][nf], 0, 0, 0);
        LGKM0(); SCHED0();
        SBAR();
        cur ^= 1;
    }
#undef STAGE_G

    float s[4], sh[4];
    int cols[4];
#pragma unroll
    for (int nf = 0; nf < 4; ++nf) {
        int col = n0 + wn * 64 + nf * 16 + (l & 15);
        cols[nf] = col;
        if (EPI == 2) { s[nf] = 1.f; sh[nf] = bias[col]; }
        else {
            float sc = bng[col] * rsqrtf(bnv[col] + BN_EPS);
            s[nf]  = sc;
            sh[nf] = bnb[col] - bnm[col] * sc;
        }
    }
#pragma unroll
    for (int mf = 0; mf < 4; ++mf) {
#pragma unroll
        for (int j = 0; j < 4; ++j) {
            int row = m0 + wm * 64 + mf * 16 + kq * 4 + j;
#pragma unroll
            for (int nf = 0; nf < 4; ++nf) {
                float v = acc[mf][nf][j] * s[nf] + sh[nf];
                if (EPI == 1) v += b2f(res[(size_t)row * ldres + cols[nf]]);
                if (EPI != 2) v = fmaxf(v, 0.f);
                if (EPI == 2) {
                    ((float*)outp)[(size_t)row * ldc + cols[nf]] = v;
                } else {
                    ((unsigned short*)outp)[(size_t)row * ldc + cols[nf]] = f2b(v);
                }
            }
        }
    }
}

// ---------------------------------------------------------------------------
// reduce GEMM, BM=64 (grid 256 blocks): tile 64x128, BK=32, 4 waves 2x2,
// acc 2x4, counted vmcnt(3). Epilogue: BN+ReLU -> padded opad layout.
// ---------------------------------------------------------------------------
__global__ __launch_bounds__(256, 3) void mfma_gemm64_pad(
    const unsigned short* __restrict__ A,      // [16384][512]
    const unsigned short* __restrict__ Wt,     // [128][512]
    unsigned short* __restrict__ opad,
    const float* __restrict__ bng, const float* __restrict__ bnb,
    const float* __restrict__ bnm, const float* __restrict__ bnv)
{
    __shared__ short8v Asta[2][256];   // [kb 0..3][row 0..63]
    __shared__ short8v Bsta[2][512];   // [kb 0..3][col 0..127]
    const int t  = threadIdx.x;
    const int l  = t & 63, wv = t >> 6;
    const int wm = wv >> 1, wn = wv & 1;
    const int m0 = blockIdx.x << 6;

    const unsigned short* Ap = A  + (size_t)(m0 + (t & 63)) * 512 + (t >> 6) * 8;
    const unsigned short* Bp = Wt + (size_t)(t & 127) * 512 + (t >> 7) * 8;

    f32x4 acc[2][4];
#pragma unroll
    for (int mf = 0; mf < 2; ++mf)
#pragma unroll
        for (int nf = 0; nf < 4; ++nf)
#pragma unroll
            for (int j = 0; j < 4; ++j) acc[mf][nf][j] = 0.f;

    const int arow = wm * 32 + (l & 15);
    const int brow = wn * 64 + (l & 15);
    const int kq   = l >> 4;

#define STAGE_R(buf, k0)                                     \
    do {                                                     \
        gload16(Ap + (k0),      &Asta[buf][wv * 64]);        \
        gload16(Bp + (k0),      &Bsta[buf][wv * 64]);        \
        gload16(Bp + (k0) + 16, &Bsta[buf][wv * 64 + 256]);  \
    } while (0)

    STAGE_R(0, 0);
    int cur = 0;
    for (int ks = 0; ks < 16; ++ks) {
        if (ks + 1 < 16) { STAGE_R(cur ^ 1, (ks + 1) << 5); VMCNT3(); }
        else             { VMCNT0(); }
        SBAR();
        short8v af[2], bfv[4];
#pragma unroll
        for (int mf = 0; mf < 2; ++mf) af[mf]  = Asta[cur][kq * 64 + arow + mf * 16];
#pragma unroll
        for (int nf = 0; nf < 4; ++nf) bfv[nf] = Bsta[cur][kq * 128 + brow + nf * 16];
#pragma unroll
        for (int mf = 0; mf < 2; ++mf)
#pragma unroll
            for (int nf = 0; nf < 4; ++nf)
                acc[mf][nf] = __builtin_amdgcn_mfma_f32_16x16x32_bf16(
                    af[mf], bfv[nf], acc[mf][nf], 0, 0, 0);
        LGKM0(); SCHED0();
        SBAR();
        cur ^= 1;
    }
#undef STAGE_R

    float s[4], sh[4];
    int cols[4];
#pragma unroll
    for (int nf = 0; nf < 4; ++nf) {
        int col = wn * 64 + nf * 16 + (l & 15);
        cols[nf] = col;
        float sc = bng[col] * rsqrtf(bnv[col] + BN_EPS);
        s[nf]  = sc;
        sh[nf] = bnb[col] - bnm[col] * sc;
    }
#pragma unroll
    for (int mf = 0; mf < 2; ++mf) {
#pragma unroll
        for (int j = 0; j < 4; ++j) {
            int row = m0 + wm * 32 + mf * 16 + kq * 4 + j;
            int b = row >> 10, h = (row >> 5) & 31, ww = row & 31;
            size_t pbase = ((size_t)(b * 36 + h + 2) * 36 + (ww + 2)) * 128;
#pragma unroll
            for (int nf = 0; nf < 4; ++nf) {
                float v = fmaxf(acc[mf][nf][j] * s[nf] + sh[nf], 0.f);
                opad[pbase + cols[nf]] = f2b(v);
            }
        }
    }
}

// ---------------------------------------------------------------------------
// Both 3x3 convs (R6-proven): tile 64 rows x 128 oc, 18 stages
// (9 taps x 2 K=64 halves), 2-buffer + counted vmcnt(6). grid (256,2).
// ---------------------------------------------------------------------------
__global__ __launch_bounds__(256, 3) void conv_mfma(
    const unsigned short* __restrict__ opad,
    const unsigned short* __restrict__ wt_all,
    const float* __restrict__ g1, const float* __restrict__ b1,
    const float* __restrict__ m1, const float* __restrict__ v1,
    const float* __restrict__ g2, const float* __restrict__ b2,
    const float* __restrict__ m2, const float* __restrict__ v2,
    unsigned short* __restrict__ lg)
{
    __shared__ short8v Asta[2][512];    // [kb 0..7][row 0..63]
    __shared__ short8v Bsta[2][1024];   // [kb 0..7][oc 0..127]
    const int t = threadIdx.x;
    const int l = t & 63, wv = t >> 6;
    const int wm = wv >> 1, wn = wv & 1;
    const int m0 = blockIdx.x << 6;
    const int br = blockIdx.y;
    const int dil = 1 + br;
    const unsigned short* wtb = wt_all + (size_t)br * 147456;

    const int r0 = t & 63;
    const int m  = m0 + r0;
    const int bb = m >> 10, h = (m >> 5) & 31, wc = m & 31;
    const ptrdiff_t pbase = ((ptrdiff_t)(bb * 36 + h + 2) * 36 + (wc + 2)) * 128;
    const unsigned short* ApT = opad + pbase + (t >> 6) * 8;
    const unsigned short* BpT = wtb + (size_t)(t & 127) * 128 + (t >> 7) * 8;

    f32x4 acc[2][4];
#pragma unroll
    for (int mf = 0; mf < 2; ++mf)
#pragma unroll
        for (int nf = 0; nf < 4; ++nf)
#pragma unroll
            for (int j = 0; j < 4; ++j) acc[mf][nf][j] = 0.f;

    const int arow = wm * 32 + (l & 15);
    const int bcol = wn * 64 + (l & 15);
    const int kq   = l >> 4;

#define STAGE_C(buf, s)                                                        \
    do {                                                                       \
        int tap_ = (s) >> 1, hh_ = ((s) & 1) * 64;                             \
        int dh_ = tap_ / 3 - 1, dw_ = tap_ % 3 - 1;                            \
        const unsigned short* Ap_ = ApT + (ptrdiff_t)((dh_ * 36 + dw_) * dil) * 128 + hh_; \
        const unsigned short* Bp_ = BpT + (size_t)tap_ * 16384 + hh_;          \
        gload16(Ap_,      &Asta[buf][wv * 64]);                                \
        gload16(Ap_ + 32, &Asta[buf][wv * 64 + 256]);                          \
        gload16(Bp_,      &Bsta[buf][wv * 64]);                                \
        gload16(Bp_ + 16, &Bsta[buf][wv * 64 + 256]);                          \
        gload16(Bp_ + 32, &Bsta[buf][wv * 64 + 512]);                          \
        gload16(Bp_ + 48, &Bsta[buf][wv * 64 + 768]);                          \
    } while (0)

    STAGE_C(0, 0);
    int cur = 0;
    for (int s = 0; s < 18; ++s) {
        if (s + 1 < 18) { STAGE_C(cur ^ 1, s + 1); VMCNT6(); }
        else            { VMCNT0(); }
        SBAR();
        short8v af[2][2], bfv[2][4];
#pragma unroll
        for (int kk = 0; kk < 2; ++kk) {
            int kb = kk * 4 + kq;
            af[kk][0] = Asta[cur][kb * 64 + arow];
            af[kk][1] = Asta[cur][kb * 64 + arow + 16];
#pragma unroll
            for (int nf = 0; nf < 4; ++nf)
                bfv[kk][nf] = Bsta[cur][kb * 128 + bcol + nf * 16];
        }
#pragma unroll
        for (int kk = 0; kk < 2; ++kk)
#pragma unroll
            for (int mf = 0; mf < 2; ++mf)
#pragma unroll
                for (int nf = 0; nf < 4; ++nf)
                    acc[mf][nf] = __builtin_amdgcn_mfma_f32_16x16x32_bf16(
                        af[kk][mf], bfv[kk][nf], acc[mf][nf], 0, 0, 0);
        LGKM0(); SCHED0();
        SBAR();
        cur ^= 1;
    }
#undef STAGE_C

    const float* gg = br ? g2 : g1;
    const float* gb = br ? b2 : b1;
    const float* gm = br ? m2 : m1;
    const float* gv = br ? v2 : v1;
    float s4[4], sh[4];
    int cols[4];
#pragma unroll
    for (int nf = 0; nf < 4; ++nf) {
        int col = bcol + nf * 16;
        cols[nf] = col;
        float sc = gg[col] * rsqrtf(gv[col] + BN_EPS);
        s4[nf] = sc;
        sh[nf] = gb[col] - gm[col] * sc;
    }
#pragma unroll
    for (int mf = 0; mf < 2; ++mf) {
#pragma unroll
        for (int j = 0; j < 4; ++j) {
            int row = m0 + wm * 32 + mf * 16 + kq * 4 + j;
#pragma unroll
            for (int nf = 0; nf < 4; ++nf) {
                float v = fmaxf(acc[mf][nf][j] * s4[nf] + sh[nf], 0.f);
                lg[(size_t)row * 256 + br * 128 + cols[nf]] = f2b(v);
            }
        }
    }
}

// ---------------------------------------------------------------------------
// L2-normalize rows of fp32 [16384][512] in place; also write bf16 copy.
// ---------------------------------------------------------------------------
__global__ __launch_bounds__(256) void l2norm_rows(
    float* __restrict__ x, unsigned short* __restrict__ xn)
{
    const int t    = threadIdx.x;
    const int wv   = t >> 6, lane = t & 63;
    const int row  = (blockIdx.x << 2) + wv;
    float* p = x + (size_t)row * 512 + (lane << 3);
    float4 a = *(float4*)p;
    float4 b = *(float4*)(p + 4);
    float ss = a.x * a.x + a.y * a.y + a.z * a.z + a.w * a.w +
               b.x * b.x + b.y * b.y + b.z * b.z + b.w * b.w;
#pragma unroll
    for (int off = 32; off >= 1; off >>= 1) ss += __shfl_xor(ss, off);
    float sc = 1.f / fmaxf(sqrtf(ss), 1e-12f);
    a.x *= sc; a.y *= sc; a.z *= sc; a.w *= sc;
    b.x *= sc; b.y *= sc; b.z *= sc; b.w *= sc;
    *(float4*)p       = a;
    *(float4*)(p + 4) = b;
    ushort8v r;
    r[0] = f2b(a.x); r[1] = f2b(a.y); r[2] = f2b(a.z); r[3] = f2b(a.w);
    r[4] = f2b(b.x); r[5] = f2b(b.y); r[6] = f2b(b.z); r[7] = f2b(b.w);
    *(ushort8v*)(xn + (size_t)row * 512 + (lane << 3)) = r;
}

// ---------------------------------------------------------------------------
// sims + per-class max (R5-EXACT, measured best): tile 128 rows x 128
// protos = 2 classes per block. grid (128, 10). BK=32, dbuf+syncthreads.
// ---------------------------------------------------------------------------
__global__ __launch_bounds__(256, 3) void sims_mfma(
    const unsigned short* __restrict__ xn,
    const unsigned short* __restrict__ protos,
    float* __restrict__ act)
{
    __shared__ short8v Asta[2][512];
    __shared__ short8v Bsta[2][512];
    const int t = threadIdx.x;
    const int l = t & 63, wv = t >> 6;
    const int wm = wv >> 1, wn = wv & 1;
    const int m0 = blockIdx.x << 7;

    const int r0  = t & 127, kb0 = t >> 7;
    const unsigned short* Ap = xn + (size_t)(m0 + r0) * 512 + kb0 * 8;
    const unsigned short* Bp = protos + ((size_t)blockIdx.y * 128 + r0) * 512 + kb0 * 8;

    f32x4 acc[4][4];
#pragma unroll
    for (int mf = 0; mf < 4; ++mf)
#pragma unroll
        for (int nf = 0; nf < 4; ++nf)
#pragma unroll
            for (int j = 0; j < 4; ++j) acc[mf][nf][j] = 0.f;

    const int arow = wm * 64 + (l & 15);
    const int brow = wn * 64 + (l & 15);
    const int kq   = l >> 4;

#define STAGE_S(buf, k0)                                     \
    do {                                                     \
        gload16(Ap + (k0),      &Asta[buf][wv * 64]);        \
        gload16(Ap + (k0) + 16, &Asta[buf][wv * 64 + 256]);  \
        gload16(Bp + (k0),      &Bsta[buf][wv * 64]);        \
        gload16(Bp + (k0) + 16, &Bsta[buf][wv * 64 + 256]);  \
    } while (0)

    STAGE_S(0, 0);
    __syncthreads();
    int cur = 0;
    for (int ks = 0; ks < 16; ++ks) {
        short8v af[4], bfv[4];
#pragma unroll
        for (int mf = 0; mf < 4; ++mf) af[mf]  = Asta[cur][kq * 128 + arow + mf * 16];
#pragma unroll
        for (int nf = 0; nf < 4; ++nf) bfv[nf] = Bsta[cur][kq * 128 + brow + nf * 16];
        if (ks + 1 < 16) STAGE_S(cur ^ 1, (ks + 1) << 5);
#pragma unroll
        for (int mf = 0; mf < 4; ++mf)
#pragma unroll
            for (int nf = 0; nf < 4; ++nf)
                acc[mf][nf] = __builtin_amdgcn_mfma_f32_16x16x32_bf16(
                    af[mf], bfv[nf], acc[mf][nf], 0, 0, 0);
        __syncthreads();
        cur ^= 1;
    }
#undef STAGE_S

    const int c = (blockIdx.y << 1) + wn;  // this wave's class
#pragma unroll
    for (int mf = 0; mf < 4; ++mf) {
        float vj[4];
#pragma unroll
        for (int j = 0; j < 4; ++j) {
            float v = fmaxf(fmaxf(acc[mf][0][j], acc[mf][1][j]),
                            fmaxf(acc[mf][2][j], acc[mf][3][j]));
            v = fmaxf(v, __shfl_xor(v, 1));
            v = fmaxf(v, __shfl_xor(v, 2));
            v = fmaxf(v, __shfl_xor(v, 4));
            v = fmaxf(v, __shfl_xor(v, 8));
            vj[j] = v;
        }
        if ((l & 15) == 0) {
            int rowb = m0 + wm * 64 + mf * 16 + kq * 4;
#pragma unroll
            for (int j = 0; j < 4; ++j) {
                int row = rowb + j;
                int bb = row >> 10, n = row & 1023;
                act[(((size_t)(bb * 20 + c)) << 10) + n] = vj[j];
            }
        }
    }
}

// ---------------------------------------------------------------------------
__global__ __launch_bounds__(256) void logits_max(
    const float* __restrict__ act, const float* __restrict__ lsc,
    float* __restrict__ logits)
{
    const int bc = blockIdx.x;
    const int t  = threadIdx.x;
    float4 v = *(const float4*)(act + ((size_t)bc << 10) + (t << 2));
    float mx = fmaxf(fmaxf(v.x, v.y), fmaxf(v.z, v.w));
#pragma unroll
    for (int off = 32; off >= 1; off >>= 1) mx = fmaxf(mx, __shfl_xor(mx, off));
    __shared__ float wmred[4];
    if ((t & 63) == 0) wmred[t >> 6] = mx;
    __syncthreads();
    if (t == 0) {
        float m2 = fmaxf(fmaxf(wmred[0], wmred[1]), fmaxf(wmred[2], wmred[3]));
        logits[bc] = m2 * lsc[0];
    }
}

// ---------------------------------------------------------------------------
extern "C" void kernel_launch(void* const* d_in, const int* in_sizes, int n_in,
                              void* d_out, int out_size, void* d_ws, size_t ws_size,
                              hipStream_t stream)
{
    const float* pf   = (const float*)d_in[0];
    const float* prot = (const float*)d_in[1];
    const float* w0   = (const float*)d_in[2];
    const float* g0   = (const float*)d_in[3];
    const float* b0   = (const float*)d_in[4];
    const float* m0v  = (const float*)d_in[5];
    const float* v0   = (const float*)d_in[6];
    const float* wr   = (const float*)d_in[7];
    const float* gr   = (const float*)d_in[8];
    const float* br   = (const float*)d_in[9];
    const float* mr   = (const float*)d_in[10];
    const float* vr   = (const float*)d_in[11];
    const float* wl   = (const float*)d_in[12];
    const float* gl   = (const float*)d_in[13];
    const float* bl   = (const float*)d_in[14];
    const float* ml   = (const float*)d_in[15];
    const float* vl   = (const float*)d_in[16];
    const float* wg   = (const float*)d_in[17];
    const float* gG   = (const float*)d_in[18];
    const float* bG   = (const float*)d_in[19];
    const float* mG   = (const float*)d_in[20];
    const float* vG   = (const float*)d_in[21];
    const float* wp   = (const float*)d_in[22];
    const float* gp   = (const float*)d_in[23];
    const float* bp   = (const float*)d_in[24];
    const float* mp   = (const float*)d_in[25];
    const float* vp   = (const float*)d_in[26];
    const float* wf   = (const float*)d_in[27];
    const float* bf_  = (const float*)d_in[28];
    const float* lsc  = (const float*)d_in[29];

    char* ws = (char*)d_ws;
    unsigned short* w0_bf    = (unsigned short*)(ws);             // 786432 B
    unsigned short* wr_bf    = (unsigned short*)(ws + 786432);    // 131072
    unsigned short* wt_bf    = (unsigned short*)(ws + 917504);    // 589824
    unsigned short* wp_bf    = (unsigned short*)(ws + 1507328);   // 262144
    unsigned short* wf_bf    = (unsigned short*)(ws + 1769472);   // 524288
    unsigned short* prot_bf  = (unsigned short*)(ws + 2293760);   // 1310720
    unsigned short* x1_bf    = (unsigned short*)(ws + 3604480);   // 16777216
    unsigned short* opad     = (unsigned short*)(ws + 20381696);  // 5308416
    unsigned short* lg_bf    = (unsigned short*)(ws + 25690112);  // 8388608
    unsigned short* x2_bf    = (unsigned short*)(ws + 34078720);  // 16777216
    unsigned short* xn_bf    = (unsigned short*)(ws + 50855936);  // 16777216

    float* out    = (float*)d_out;
    float* logits = out;            // [16][20]
    float* act    = out + 320;      // [16][20][1024]
    float* xo     = out + 328000;   // [16384][512] fp32

    // ---- weight/proto conversions + conv transpose + opad zero ----
    prep_all<<<2176, 256, 0, stream>>>(
        w0, wr, wp, wf, prot, wl, wg,
        w0_bf, wr_bf, wp_bf, wf_bf, prot_bf, wt_bf, opad);

    // ---- adapter: fp32 pf x w0^T -> BN -> ReLU -> x1 (bf16), depth-2 ----
    mfma_gemm_f32a<<<dim3(128, 4), 256, 0, stream>>>(
        pf, 768, w0_bf, 768, x1_bf, 512, 768, g0, b0, m0v, v0);

    // ---- reduce: x1 x wr^T -> BN -> ReLU -> opad (BM=64, 256 blocks) ----
    mfma_gemm64_pad<<<256, 256, 0, stream>>>(
        x1_bf, wr_bf, opad, gr, br, mr, vr);

    // ---- both 3x3 conv branches -> lg (bf16 [16384][256]) ----
    conv_mfma<<<dim3(256, 2), 256, 0, stream>>>(
        opad, wt_bf, gl, bl, ml, vl, gG, bG, mG, vG, lg_bf);

    // ---- project: lg x wp^T -> BN -> +x1 -> ReLU -> x2 (bf16) ----
    mfma_gemm<1><<<dim3(128, 4), 256, 0, stream>>>(
        lg_bf, 256, wp_bf, 256, x2_bf, 512, 256,
        gp, bp, mp, vp, x1_bf, 512, nullptr);

    // ---- final: x2 x wf^T + bf -> xo (fp32 in d_out) ----
    mfma_gemm<2><<<dim3(128, 4), 256, 0, stream>>>(
        x2_bf, 512, wf_bf, 512, xo, 512, 512,
        nullptr, nullptr, nullptr, nullptr, nullptr, 0, bf_);

    // ---- L2 normalize xo in place + bf16 copy ----
    l2norm_rows<<<4096, 256, 0, stream>>>(xo, xn_bf);

    // ---- sims + max over protos -> act (2 classes / block) ----
    sims_mfma<<<dim3(128, 10), 256, 0, stream>>>(xn_bf, prot_bf, act);

    // ---- logits ----
    logits_max<<<320, 256, 0, stream>>>(act, lsc, logits);
}

// Round 15
// 188.495 us; speedup vs baseline: 1.0144x; 1.0144x over previous
//
#include <hip/hip_runtime.h>
#include <math.h>

#define BN_EPS 1e-5f

typedef __attribute__((ext_vector_type(8))) short short8v;   // 8 x bf16 bits
typedef __attribute__((ext_vector_type(8))) unsigned short ushort8v;
typedef __attribute__((ext_vector_type(4))) float f32x4;

__device__ __forceinline__ unsigned short f2b(float f) {
    unsigned int u = __float_as_uint(f);
    return (unsigned short)((u + 0x7FFFu + ((u >> 16) & 1u)) >> 16);
}
__device__ __forceinline__ float b2f(unsigned short h) {
    return __uint_as_float(((unsigned int)h) << 16);
}

typedef __attribute__((address_space(1))) const unsigned int gas_uint;
typedef __attribute__((address_space(3))) unsigned int las_uint;
__device__ __forceinline__ void gload16(const void* g, void* l) {
    __builtin_amdgcn_global_load_lds((gas_uint*)g, (las_uint*)l, 16, 0, 0);
}

#define VMCNT2()  asm volatile("s_waitcnt vmcnt(2)"  ::: "memory")
#define VMCNT3()  asm volatile("s_waitcnt vmcnt(3)"  ::: "memory")
#define VMCNT4()  asm volatile("s_waitcnt vmcnt(4)"  ::: "memory")
#define VMCNT6()  asm volatile("s_waitcnt vmcnt(6)"  ::: "memory")
#define VMCNT0()  asm volatile("s_waitcnt vmcnt(0)"  ::: "memory")
#define LGKM0()   asm volatile("s_waitcnt lgkmcnt(0)" ::: "memory")
#define SBAR()    __builtin_amdgcn_s_barrier()
#define SCHED0()  __builtin_amdgcn_sched_barrier(0)

// ---------------------------------------------------------------------------
// prep_all: weight/proto conversions + conv transpose + opad zero.
// ---------------------------------------------------------------------------
__global__ __launch_bounds__(256) void prep_all(
    const float* __restrict__ w0,  const float* __restrict__ wr,
    const float* __restrict__ wp,  const float* __restrict__ wf,
    const float* __restrict__ prot,
    const float* __restrict__ wl,  const float* __restrict__ wg,
    unsigned short* __restrict__ w0_o, unsigned short* __restrict__ wr_o,
    unsigned short* __restrict__ wp_o, unsigned short* __restrict__ wf_o,
    unsigned short* __restrict__ prot_o,
    unsigned short* __restrict__ wt_o, unsigned short* __restrict__ opad)
{
    int i = blockIdx.x * 256 + threadIdx.x;
    if (i >= 557056) return;
    if (i >= 225280) {                // zero opad
        ushort8v z;
#pragma unroll
        for (int k = 0; k < 8; ++k) z[k] = 0;
        *(ushort8v*)(opad + (size_t)(i - 225280) * 8) = z;
        return;
    }
    if (i >= 188416) {                // conv weight transpose (gather)
        int e0 = (i - 188416) * 8;
        ushort8v u;
#pragma unroll
        for (int q = 0; q < 8; ++q) {
            int e = e0 + q;
            int br = e >= 147456;
            int j  = e - br * 147456;
            int tap = j >> 14, oc = (j >> 7) & 127, ic = j & 127;
            const float* src = br ? wg : wl;
            u[q] = f2b(src[((oc << 7) + ic) * 9 + tap]);
        }
        *(ushort8v*)(wt_o + (size_t)e0) = u;
        return;
    }
    const float* src; unsigned short* dst; int off;
    if      (i <  49152) { src = w0;   dst = w0_o;   off = i; }
    else if (i <  57344) { src = wr;   dst = wr_o;   off = i - 49152; }
    else if (i <  73728) { src = wp;   dst = wp_o;   off = i - 57344; }
    else if (i < 106496) { src = wf;   dst = wf_o;   off = i - 73728; }
    else                 { src = prot; dst = prot_o; off = i - 106496; }
    const float4* p = (const float4*)(src + (size_t)off * 8);
    float4 a = p[0], b = p[1];
    ushort8v r;
    r[0] = f2b(a.x); r[1] = f2b(a.y); r[2] = f2b(a.z); r[3] = f2b(a.w);
    r[4] = f2b(b.x); r[5] = f2b(b.y); r[6] = f2b(b.z); r[7] = f2b(b.w);
    *(ushort8v*)(dst + (size_t)off * 8) = r;
}

// ---------------------------------------------------------------------------
// Adapter GEMM (R13 depth-1, + XCD remap): fp32 A converted in-kernel.
// 1D grid 512: xcd=bid%8, v=bid/8; mb=xcd*16+(v>>2), nb=v&3 — the 4 blocks
// sharing an A-panel are co-resident on one XCD -> A re-reads become L2 hits.
// ---------------------------------------------------------------------------
__global__ __launch_bounds__(256, 3) void mfma_gemm_f32a(
    const float* __restrict__ A, int lda,
    const unsigned short* __restrict__ Wt, int ldw,
    unsigned short* __restrict__ outp, int ldc, int Kdim,
    const float* __restrict__ bng, const float* __restrict__ bnb,
    const float* __restrict__ bnm, const float* __restrict__ bnv)
{
    __shared__ short8v Asta[2][512];
    __shared__ short8v Bsta[2][512];
    const int t  = threadIdx.x;
    const int l  = t & 63, wv = t >> 6;
    const int wm = wv >> 1, wn = wv & 1;

    const int bid = blockIdx.x;           // 0..511
    const int xcd = bid & 7, v = bid >> 3;
    const int m0 = (xcd * 16 + (v >> 2)) << 7;
    const int n0 = (v & 3) << 7;

    const int r0  = t & 127;
    const int kb0 = t >> 7;

    const float*          Apf = A  + (size_t)(m0 + r0) * lda + kb0 * 8;
    const unsigned short* Bp  = Wt + (size_t)(n0 + r0) * ldw + kb0 * 8;

    f32x4 acc[4][4];
#pragma unroll
    for (int mf = 0; mf < 4; ++mf)
#pragma unroll
        for (int nf = 0; nf < 4; ++nf)
#pragma unroll
            for (int j = 0; j < 4; ++j) acc[mf][nf][j] = 0.f;

    const int arow = wm * 64 + (l & 15);
    const int brow = wn * 64 + (l & 15);
    const int kq   = l >> 4;
    const int nK   = Kdim >> 5;

    float4 areg[2][2];

#define LOADA(k0)                                                   \
    do {                                                            \
        areg[0][0] = *(const float4*)(Apf + (k0));                  \
        areg[0][1] = *(const float4*)(Apf + (k0) + 4);              \
        areg[1][0] = *(const float4*)(Apf + (k0) + 16);             \
        areg[1][1] = *(const float4*)(Apf + (k0) + 20);             \
    } while (0)

#define WRITEA(buf)                                                 \
    do {                                                            \
        _Pragma("unroll")                                           \
        for (int c_ = 0; c_ < 2; ++c_) {                            \
            ushort8v u_;                                            \
            u_[0] = f2b(areg[c_][0].x); u_[1] = f2b(areg[c_][0].y); \
            u_[2] = f2b(areg[c_][0].z); u_[3] = f2b(areg[c_][0].w); \
            u_[4] = f2b(areg[c_][1].x); u_[5] = f2b(areg[c_][1].y); \
            u_[6] = f2b(areg[c_][1].z); u_[7] = f2b(areg[c_][1].w); \
            *(ushort8v*)&Asta[buf][t + 256 * c_] = u_;              \
        }                                                           \
    } while (0)

#define STAGEB(buf, k0)                                      \
    do {                                                     \
        gload16(Bp + (k0),      &Bsta[buf][wv * 64]);        \
        gload16(Bp + (k0) + 16, &Bsta[buf][wv * 64 + 256]);  \
    } while (0)

    LOADA(0);
    STAGEB(0, 0);
    VMCNT2();
    WRITEA(0);
    VMCNT0(); LGKM0();
    SBAR();

    int cur = 0;
    for (int ks = 0; ks < nK; ++ks) {
        const bool more = (ks + 1 < nK);
        if (more) {
            LOADA((ks + 1) << 5);
            STAGEB(cur ^ 1, (ks + 1) << 5);
        }
        short8v af[4], bfv[4];
#pragma unroll
        for (int mf = 0; mf < 4; ++mf) af[mf]  = Asta[cur][kq * 128 + arow + mf * 16];
#pragma unroll
        for (int nf = 0; nf < 4; ++nf) bfv[nf] = Bsta[cur][kq * 128 + brow + nf * 16];
#pragma unroll
        for (int mf = 0; mf < 4; ++mf)
#pragma unroll
            for (int nf = 0; nf < 4; ++nf)
                acc[mf][nf] = __builtin_amdgcn_mfma_f32_16x16x32_bf16(
                    af[mf], bfv[nf], acc[mf][nf], 0, 0, 0);
        if (more) {
            VMCNT2();
            WRITEA(cur ^ 1);
        }
        LGKM0(); SCHED0();
        VMCNT0();
        SBAR();
        cur ^= 1;
    }
#undef LOADA
#undef WRITEA
#undef STAGEB

    float s[4], sh[4];
    int cols[4];
#pragma unroll
    for (int nf = 0; nf < 4; ++nf) {
        int col = n0 + wn * 64 + nf * 16 + (l & 15);
        cols[nf] = col;
        float sc = bng[col] * rsqrtf(bnv[col] + BN_EPS);
        s[nf]  = sc;
        sh[nf] = bnb[col] - bnm[col] * sc;
    }
#pragma unroll
    for (int mf = 0; mf < 4; ++mf) {
#pragma unroll
        for (int j = 0; j < 4; ++j) {
            int row = m0 + wm * 64 + mf * 16 + kq * 4 + j;
#pragma unroll
            for (int nf = 0; nf < 4; ++nf) {
                float v2 = fmaxf(acc[mf][nf][j] * s[nf] + sh[nf], 0.f);
                outp[(size_t)row * ldc + cols[nf]] = f2b(v2);
            }
        }
    }
}

// ---------------------------------------------------------------------------
// bf16 MFMA NT GEMM (R6-proven + XCD remap): tile 128x128, BK=32, 4 waves,
// acc 4x4, 2-buffer LDS + counted vmcnt(4). 1D grid 512 (x=bid).
// EPI 1: BN+res+ReLU->bf16  2: +bias->fp32
// ---------------------------------------------------------------------------
template <int EPI>
__global__ __launch_bounds__(256, 3) void mfma_gemm(
    const unsigned short* __restrict__ A, int lda,
    const unsigned short* __restrict__ Wt, int ldw,
    void* __restrict__ outp, int ldc, int Kdim,
    const float* __restrict__ bng, const float* __restrict__ bnb,
    const float* __restrict__ bnm, const float* __restrict__ bnv,
    const unsigned short* __restrict__ res, int ldres,
    const float* __restrict__ bias)
{
    __shared__ short8v Asta[2][512];
    __shared__ short8v Bsta[2][512];
    const int t  = threadIdx.x;
    const int l  = t & 63, wv = t >> 6;
    const int wm = wv >> 1, wn = wv & 1;

    const int bid = blockIdx.x;           // 0..511
    const int xcd = bid & 7, v = bid >> 3;
    const int m0 = (xcd * 16 + (v >> 2)) << 7;
    const int n0 = (v & 3) << 7;

    const int r0  = t & 127;
    const int kb0 = t >> 7;

    const unsigned short* Ap = A  + (size_t)(m0 + r0) * lda + kb0 * 8;
    const unsigned short* Bp = Wt + (size_t)(n0 + r0) * ldw + kb0 * 8;

    f32x4 acc[4][4];
#pragma unroll
    for (int mf = 0; mf < 4; ++mf)
#pragma unroll
        for (int nf = 0; nf < 4; ++nf)
#pragma unroll
            for (int j = 0; j < 4; ++j) acc[mf][nf][j] = 0.f;

    const int arow = wm * 64 + (l & 15);
    const int brow = wn * 64 + (l & 15);
    const int kq   = l >> 4;
    const int nK   = Kdim >> 5;

#define STAGE_G(buf, k0)                                     \
    do {                                                     \
        gload16(Ap + (k0),      &Asta[buf][wv * 64]);        \
        gload16(Ap + (k0) + 16, &Asta[buf][wv * 64 + 256]);  \
        gload16(Bp + (k0),      &Bsta[buf][wv * 64]);        \
        gload16(Bp + (k0) + 16, &Bsta[buf][wv * 64 + 256]);  \
    } while (0)

    STAGE_G(0, 0);
    int cur = 0;
    for (int ks = 0; ks < nK; ++ks) {
        if (ks + 1 < nK) { STAGE_G(cur ^ 1, (ks + 1) << 5); VMCNT4(); }
        else             { VMCNT0(); }
        SBAR();
        short8v af[4], bfv[4];
#pragma unroll
        for (int mf = 0; mf < 4; ++mf) af[mf]  = Asta[cur][kq * 128 + arow + mf * 16];
#pragma unroll
        for (int nf = 0; nf < 4; ++nf) bfv[nf] = Bsta[cur][kq * 128 + brow + nf * 16];
#pragma unroll
        for (int mf = 0; mf < 4; ++mf)
#pragma unroll
            for (int nf = 0; nf < 4; ++nf)
                acc[mf][nf] = __builtin_amdgcn_mfma_f32_16x16x32_bf16(
                    af[mf], bfv[nf], acc[mf][nf], 0, 0, 0);
        LGKM0(); SCHED0();
        SBAR();
        cur ^= 1;
    }
#undef STAGE_G

    float s[4], sh[4];
    int cols[4];
#pragma unroll
    for (int nf = 0; nf < 4; ++nf) {
        int col = n0 + wn * 64 + nf * 16 + (l & 15);
        cols[nf] = col;
        if (EPI == 2) { s[nf] = 1.f; sh[nf] = bias[col]; }
        else {
            float sc = bng[col] * rsqrtf(bnv[col] + BN_EPS);
            s[nf]  = sc;
            sh[nf] = bnb[col] - bnm[col] * sc;
        }
    }
#pragma unroll
    for (int mf = 0; mf < 4; ++mf) {
#pragma unroll
        for (int j = 0; j < 4; ++j) {
            int row = m0 + wm * 64 + mf * 16 + kq * 4 + j;
#pragma unroll
            for (int nf = 0; nf < 4; ++nf) {
                float v2 = acc[mf][nf][j] * s[nf] + sh[nf];
                if (EPI == 1) v2 += b2f(res[(size_t)row * ldres + cols[nf]]);
                if (EPI != 2) v2 = fmaxf(v2, 0.f);
                if (EPI == 2) {
                    ((float*)outp)[(size_t)row * ldc + cols[nf]] = v2;
                } else {
                    ((unsigned short*)outp)[(size_t)row * ldc + cols[nf]] = f2b(v2);
                }
            }
        }
    }
}

// ---------------------------------------------------------------------------
// reduce GEMM, BM=64 (grid 256 blocks): unchanged (no A reuse to exploit).
// ---------------------------------------------------------------------------
__global__ __launch_bounds__(256, 3) void mfma_gemm64_pad(
    const unsigned short* __restrict__ A,
    const unsigned short* __restrict__ Wt,
    unsigned short* __restrict__ opad,
    const float* __restrict__ bng, const float* __restrict__ bnb,
    const float* __restrict__ bnm, const float* __restrict__ bnv)
{
    __shared__ short8v Asta[2][256];
    __shared__ short8v Bsta[2][512];
    const int t  = threadIdx.x;
    const int l  = t & 63, wv = t >> 6;
    const int wm = wv >> 1, wn = wv & 1;
    const int m0 = blockIdx.x << 6;

    const unsigned short* Ap = A  + (size_t)(m0 + (t & 63)) * 512 + (t >> 6) * 8;
    const unsigned short* Bp = Wt + (size_t)(t & 127) * 512 + (t >> 7) * 8;

    f32x4 acc[2][4];
#pragma unroll
    for (int mf = 0; mf < 2; ++mf)
#pragma unroll
        for (int nf = 0; nf < 4; ++nf)
#pragma unroll
            for (int j = 0; j < 4; ++j) acc[mf][nf][j] = 0.f;

    const int arow = wm * 32 + (l & 15);
    const int brow = wn * 64 + (l & 15);
    const int kq   = l >> 4;

#define STAGE_R(buf, k0)                                     \
    do {                                                     \
        gload16(Ap + (k0),      &Asta[buf][wv * 64]);        \
        gload16(Bp + (k0),      &Bsta[buf][wv * 64]);        \
        gload16(Bp + (k0) + 16, &Bsta[buf][wv * 64 + 256]);  \
    } while (0)

    STAGE_R(0, 0);
    int cur = 0;
    for (int ks = 0; ks < 16; ++ks) {
        if (ks + 1 < 16) { STAGE_R(cur ^ 1, (ks + 1) << 5); VMCNT3(); }
        else             { VMCNT0(); }
        SBAR();
        short8v af[2], bfv[4];
#pragma unroll
        for (int mf = 0; mf < 2; ++mf) af[mf]  = Asta[cur][kq * 64 + arow + mf * 16];
#pragma unroll
        for (int nf = 0; nf < 4; ++nf) bfv[nf] = Bsta[cur][kq * 128 + brow + nf * 16];
#pragma unroll
        for (int mf = 0; mf < 2; ++mf)
#pragma unroll
            for (int nf = 0; nf < 4; ++nf)
                acc[mf][nf] = __builtin_amdgcn_mfma_f32_16x16x32_bf16(
                    af[mf], bfv[nf], acc[mf][nf], 0, 0, 0);
        LGKM0(); SCHED0();
        SBAR();
        cur ^= 1;
    }
#undef STAGE_R

    float s[4], sh[4];
    int cols[4];
#pragma unroll
    for (int nf = 0; nf < 4; ++nf) {
        int col = wn * 64 + nf * 16 + (l & 15);
        cols[nf] = col;
        float sc = bng[col] * rsqrtf(bnv[col] + BN_EPS);
        s[nf]  = sc;
        sh[nf] = bnb[col] - bnm[col] * sc;
    }
#pragma unroll
    for (int mf = 0; mf < 2; ++mf) {
#pragma unroll
        for (int j = 0; j < 4; ++j) {
            int row = m0 + wm * 32 + mf * 16 + kq * 4 + j;
            int b = row >> 10, h = (row >> 5) & 31, ww = row & 31;
            size_t pbase = ((size_t)(b * 36 + h + 2) * 36 + (ww + 2)) * 128;
#pragma unroll
            for (int nf = 0; nf < 4; ++nf) {
                float v2 = fmaxf(acc[mf][nf][j] * s[nf] + sh[nf], 0.f);
                opad[pbase + cols[nf]] = f2b(v2);
            }
        }
    }
}

// ---------------------------------------------------------------------------
// Both 3x3 convs (R6-proven + XCD remap on x): each XCD gets 32 contiguous
// m-tiles (a contiguous image slab, ~0.7 MB input) -> opad reads L2-local.
// grid (256, 2): y = branch (dil = 1+y).
// ---------------------------------------------------------------------------
__global__ __launch_bounds__(256, 3) void conv_mfma(
    const unsigned short* __restrict__ opad,
    const unsigned short* __restrict__ wt_all,
    const float* __restrict__ g1, const float* __restrict__ b1,
    const float* __restrict__ m1, const float* __restrict__ v1,
    const float* __restrict__ g2, const float* __restrict__ b2,
    const float* __restrict__ m2, const float* __restrict__ v2,
    unsigned short* __restrict__ lg)
{
    __shared__ short8v Asta[2][512];
    __shared__ short8v Bsta[2][1024];
    const int t = threadIdx.x;
    const int l = t & 63, wv = t >> 6;
    const int wm = wv >> 1, wn = wv & 1;

    const int mbo = blockIdx.x;            // 0..255
    const int m0  = ((mbo & 7) * 32 + (mbo >> 3)) << 6;

    const int br = blockIdx.y;
    const int dil = 1 + br;
    const unsigned short* wtb = wt_all + (size_t)br * 147456;

    const int r0 = t & 63;
    const int m  = m0 + r0;
    const int bb = m >> 10, h = (m >> 5) & 31, wc = m & 31;
    const ptrdiff_t pbase = ((ptrdiff_t)(bb * 36 + h + 2) * 36 + (wc + 2)) * 128;
    const unsigned short* ApT = opad + pbase + (t >> 6) * 8;
    const unsigned short* BpT = wtb + (size_t)(t & 127) * 128 + (t >> 7) * 8;

    f32x4 acc[2][4];
#pragma unroll
    for (int mf = 0; mf < 2; ++mf)
#pragma unroll
        for (int nf = 0; nf < 4; ++nf)
#pragma unroll
            for (int j = 0; j < 4; ++j) acc[mf][nf][j] = 0.f;

    const int arow = wm * 32 + (l & 15);
    const int bcol = wn * 64 + (l & 15);
    const int kq   = l >> 4;

#define STAGE_C(buf, s)                                                        \
    do {                                                                       \
        int tap_ = (s) >> 1, hh_ = ((s) & 1) * 64;                             \
        int dh_ = tap_ / 3 - 1, dw_ = tap_ % 3 - 1;                            \
        const unsigned short* Ap_ = ApT + (ptrdiff_t)((dh_ * 36 + dw_) * dil) * 128 + hh_; \
        const unsigned short* Bp_ = BpT + (size_t)tap_ * 16384 + hh_;          \
        gload16(Ap_,      &Asta[buf][wv * 64]);                                \
        gload16(Ap_ + 32, &Asta[buf][wv * 64 + 256]);                          \
        gload16(Bp_,      &Bsta[buf][wv * 64]);                                \
        gload16(Bp_ + 16, &Bsta[buf][wv * 64 + 256]);                          \
        gload16(Bp_ + 32, &Bsta[buf][wv * 64 + 512]);                          \
        gload16(Bp_ + 48, &Bsta[buf][wv * 64 + 768]);                          \
    } while (0)

    STAGE_C(0, 0);
    int cur = 0;
    for (int s = 0; s < 18; ++s) {
        if (s + 1 < 18) { STAGE_C(cur ^ 1, s + 1); VMCNT6(); }
        else            { VMCNT0(); }
        SBAR();
        short8v af[2][2], bfv[2][4];
#pragma unroll
        for (int kk = 0; kk < 2; ++kk) {
            int kb = kk * 4 + kq;
            af[kk][0] = Asta[cur][kb * 64 + arow];
            af[kk][1] = Asta[cur][kb * 64 + arow + 16];
#pragma unroll
            for (int nf = 0; nf < 4; ++nf)
                bfv[kk][nf] = Bsta[cur][kb * 128 + bcol + nf * 16];
        }
#pragma unroll
        for (int kk = 0; kk < 2; ++kk)
#pragma unroll
            for (int mf = 0; mf < 2; ++mf)
#pragma unroll
                for (int nf = 0; nf < 4; ++nf)
                    acc[mf][nf] = __builtin_amdgcn_mfma_f32_16x16x32_bf16(
                        af[kk][mf], bfv[kk][nf], acc[mf][nf], 0, 0, 0);
        LGKM0(); SCHED0();
        SBAR();
        cur ^= 1;
    }
#undef STAGE_C

    const float* gg = br ? g2 : g1;
    const float* gb = br ? b2 : b1;
    const float* gm = br ? m2 : m1;
    const float* gv = br ? v2 : v1;
    float s4[4], sh[4];
    int cols[4];
#pragma unroll
    for (int nf = 0; nf < 4; ++nf) {
        int col = bcol + nf * 16;
        cols[nf] = col;
        float sc = gg[col] * rsqrtf(gv[col] + BN_EPS);
        s4[nf] = sc;
        sh[nf] = gb[col] - gm[col] * sc;
    }
#pragma unroll
    for (int mf = 0; mf < 2; ++mf) {
#pragma unroll
        for (int j = 0; j < 4; ++j) {
            int row = m0 + wm * 32 + mf * 16 + kq * 4 + j;
#pragma unroll
            for (int nf = 0; nf < 4; ++nf) {
                float v2 = fmaxf(acc[mf][nf][j] * s4[nf] + sh[nf], 0.f);
                lg[(size_t)row * 256 + br * 128 + cols[nf]] = f2b(v2);
            }
        }
    }
}

// ---------------------------------------------------------------------------
__global__ __launch_bounds__(256) void l2norm_rows(
    float* __restrict__ x, unsigned short* __restrict__ xn)
{
    const int t    = threadIdx.x;
    const int wv   = t >> 6, lane = t & 63;
    const int row  = (blockIdx.x << 2) + wv;
    float* p = x + (size_t)row * 512 + (lane << 3);
    float4 a = *(float4*)p;
    float4 b = *(float4*)(p + 4);
    float ss = a.x * a.x + a.y * a.y + a.z * a.z + a.w * a.w +
               b.x * b.x + b.y * b.y + b.z * b.z + b.w * b.w;
#pragma unroll
    for (int off = 32; off >= 1; off >>= 1) ss += __shfl_xor(ss, off);
    float sc = 1.f / fmaxf(sqrtf(ss), 1e-12f);
    a.x *= sc; a.y *= sc; a.z *= sc; a.w *= sc;
    b.x *= sc; b.y *= sc; b.z *= sc; b.w *= sc;
    *(float4*)p       = a;
    *(float4*)(p + 4) = b;
    ushort8v r;
    r[0] = f2b(a.x); r[1] = f2b(a.y); r[2] = f2b(a.z); r[3] = f2b(a.w);
    r[4] = f2b(b.x); r[5] = f2b(b.y); r[6] = f2b(b.z); r[7] = f2b(b.w);
    *(ushort8v*)(xn + (size_t)row * 512 + (lane << 3)) = r;
}

// ---------------------------------------------------------------------------
// sims + per-class max (R5 loop + XCD remap): 1D grid 1280. xcd=bid%8,
// v=bid/8 (0..159); mb=xcd*16+v/10, cp=v%10 — all 10 class-pair blocks of
// one 128-row A-panel are co-resident on one XCD (2 MB A + 1.3 MB B in L2).
// ---------------------------------------------------------------------------
__global__ __launch_bounds__(256, 3) void sims_mfma(
    const unsigned short* __restrict__ xn,
    const unsigned short* __restrict__ protos,
    float* __restrict__ act)
{
    __shared__ short8v Asta[2][512];
    __shared__ short8v Bsta[2][512];
    const int t = threadIdx.x;
    const int l = t & 63, wv = t >> 6;
    const int wm = wv >> 1, wn = wv & 1;

    const int bid = blockIdx.x;            // 0..1279
    const int xcd = bid & 7, v = bid >> 3;  // v: 0..159
    const int mb  = xcd * 16 + v / 10;
    const int cp  = v % 10;
    const int m0  = mb << 7;

    const int r0  = t & 127, kb0 = t >> 7;
    const unsigned short* Ap = xn + (size_t)(m0 + r0) * 512 + kb0 * 8;
    const unsigned short* Bp = protos + ((size_t)cp * 128 + r0) * 512 + kb0 * 8;

    f32x4 acc[4][4];
#pragma unroll
    for (int mf = 0; mf < 4; ++mf)
#pragma unroll
        for (int nf = 0; nf < 4; ++nf)
#pragma unroll
            for (int j = 0; j < 4; ++j) acc[mf][nf][j] = 0.f;

    const int arow = wm * 64 + (l & 15);
    const int brow = wn * 64 + (l & 15);
    const int kq   = l >> 4;

#define STAGE_S(buf, k0)                                     \
    do {                                                     \
        gload16(Ap + (k0),      &Asta[buf][wv * 64]);        \
        gload16(Ap + (k0) + 16, &Asta[buf][wv * 64 + 256]);  \
        gload16(Bp + (k0),      &Bsta[buf][wv * 64]);        \
        gload16(Bp + (k0) + 16, &Bsta[buf][wv * 64 + 256]);  \
    } while (0)

    STAGE_S(0, 0);
    __syncthreads();
    int cur = 0;
    for (int ks = 0; ks < 16; ++ks) {
        short8v af[4], bfv[4];
#pragma unroll
        for (int mf = 0; mf < 4; ++mf) af[mf]  = Asta[cur][kq * 128 + arow + mf * 16];
#pragma unroll
        for (int nf = 0; nf < 4; ++nf) bfv[nf] = Bsta[cur][kq * 128 + brow + nf * 16];
        if (ks + 1 < 16) STAGE_S(cur ^ 1, (ks + 1) << 5);
#pragma unroll
        for (int mf = 0; mf < 4; ++mf)
#pragma unroll
            for (int nf = 0; nf < 4; ++nf)
                acc[mf][nf] = __builtin_amdgcn_mfma_f32_16x16x32_bf16(
                    af[mf], bfv[nf], acc[mf][nf], 0, 0, 0);
        __syncthreads();
        cur ^= 1;
    }
#undef STAGE_S

    const int c = (cp << 1) + wn;  // this wave's class
#pragma unroll
    for (int mf = 0; mf < 4; ++mf) {
        float vj[4];
#pragma unroll
        for (int j = 0; j < 4; ++j) {
            float vx = fmaxf(fmaxf(acc[mf][0][j], acc[mf][1][j]),
                             fmaxf(acc[mf][2][j], acc[mf][3][j]));
            vx = fmaxf(vx, __shfl_xor(vx, 1));
            vx = fmaxf(vx, __shfl_xor(vx, 2));
            vx = fmaxf(vx, __shfl_xor(vx, 4));
            vx = fmaxf(vx, __shfl_xor(vx, 8));
            vj[j] = vx;
        }
        if ((l & 15) == 0) {
            int rowb = m0 + wm * 64 + mf * 16 + kq * 4;
#pragma unroll
            for (int j = 0; j < 4; ++j) {
                int row = rowb + j;
                int bb = row >> 10, n = row & 1023;
                act[(((size_t)(bb * 20 + c)) << 10) + n] = vj[j];
            }
        }
    }
}

// ---------------------------------------------------------------------------
__global__ __launch_bounds__(256) void logits_max(
    const float* __restrict__ act, const float* __restrict__ lsc,
    float* __restrict__ logits)
{
    const int bc = blockIdx.x;
    const int t  = threadIdx.x;
    float4 v = *(const float4*)(act + ((size_t)bc << 10) + (t << 2));
    float mx = fmaxf(fmaxf(v.x, v.y), fmaxf(v.z, v.w));
#pragma unroll
    for (int off = 32; off >= 1; off >>= 1) mx = fmaxf(mx, __shfl_xor(mx, off));
    __shared__ float wmred[4];
    if ((t & 63) == 0) wmred[t >> 6] = mx;
    __syncthreads();
    if (t == 0) {
        float m2 = fmaxf(fmaxf(wmred[0], wmred[1]), fmaxf(wmred[2], wmred[3]));
        logits[bc] = m2 * lsc[0];
    }
}

// ---------------------------------------------------------------------------
extern "C" void kernel_launch(void* const* d_in, const int* in_sizes, int n_in,
                              void* d_out, int out_size, void* d_ws, size_t ws_size,
                              hipStream_t stream)
{
    const float* pf   = (const float*)d_in[0];
    const float* prot = (const float*)d_in[1];
    const float* w0   = (const float*)d_in[2];
    const float* g0   = (const float*)d_in[3];
    const float* b0   = (const float*)d_in[4];
    const float* m0v  = (const float*)d_in[5];
    const float* v0   = (const float*)d_in[6];
    const float* wr   = (const float*)d_in[7];
    const float* gr   = (const float*)d_in[8];
    const float* br   = (const float*)d_in[9];
    const float* mr   = (const float*)d_in[10];
    const float* vr   = (const float*)d_in[11];
    const float* wl   = (const float*)d_in[12];
    const float* gl   = (const float*)d_in[13];
    const float* bl   = (const float*)d_in[14];
    const float* ml   = (const float*)d_in[15];
    const float* vl   = (const float*)d_in[16];
    const float* wg   = (const float*)d_in[17];
    const float* gG   = (const float*)d_in[18];
    const float* bG   = (const float*)d_in[19];
    const float* mG   = (const float*)d_in[20];
    const float* vG   = (const float*)d_in[21];
    const float* wp   = (const float*)d_in[22];
    const float* gp   = (const float*)d_in[23];
    const float* bp   = (const float*)d_in[24];
    const float* mp   = (const float*)d_in[25];
    const float* vp   = (const float*)d_in[26];
    const float* wf   = (const float*)d_in[27];
    const float* bf_  = (const float*)d_in[28];
    const float* lsc  = (const float*)d_in[29];

    char* ws = (char*)d_ws;
    unsigned short* w0_bf    = (unsigned short*)(ws);             // 786432 B
    unsigned short* wr_bf    = (unsigned short*)(ws + 786432);    // 131072
    unsigned short* wt_bf    = (unsigned short*)(ws + 917504);    // 589824
    unsigned short* wp_bf    = (unsigned short*)(ws + 1507328);   // 262144
    unsigned short* wf_bf    = (unsigned short*)(ws + 1769472);   // 524288
    unsigned short* prot_bf  = (unsigned short*)(ws + 2293760);   // 1310720
    unsigned short* x1_bf    = (unsigned short*)(ws + 3604480);   // 16777216
    unsigned short* opad     = (unsigned short*)(ws + 20381696);  // 5308416
    unsigned short* lg_bf    = (unsigned short*)(ws + 25690112);  // 8388608
    unsigned short* x2_bf    = (unsigned short*)(ws + 34078720);  // 16777216
    unsigned short* xn_bf    = (unsigned short*)(ws + 50855936);  // 16777216

    float* out    = (float*)d_out;
    float* logits = out;            // [16][20]
    float* act    = out + 320;      // [16][20][1024]
    float* xo     = out + 328000;   // [16384][512] fp32

    // ---- weight/proto conversions + conv transpose + opad zero ----
    prep_all<<<2176, 256, 0, stream>>>(
        w0, wr, wp, wf, prot, wl, wg,
        w0_bf, wr_bf, wp_bf, wf_bf, prot_bf, wt_bf, opad);

    // ---- adapter: fp32 pf x w0^T -> BN -> ReLU -> x1 (bf16), XCD-remap ----
    mfma_gemm_f32a<<<512, 256, 0, stream>>>(
        pf, 768, w0_bf, 768, x1_bf, 512, 768, g0, b0, m0v, v0);

    // ---- reduce: x1 x wr^T -> BN -> ReLU -> opad (BM=64, 256 blocks) ----
    mfma_gemm64_pad<<<256, 256, 0, stream>>>(
        x1_bf, wr_bf, opad, gr, br, mr, vr);

    // ---- both 3x3 conv branches -> lg (bf16 [16384][256]) ----
    conv_mfma<<<dim3(256, 2), 256, 0, stream>>>(
        opad, wt_bf, gl, bl, ml, vl, gG, bG, mG, vG, lg_bf);

    // ---- project: lg x wp^T -> BN -> +x1 -> ReLU -> x2 (bf16) ----
    mfma_gemm<1><<<512, 256, 0, stream>>>(
        lg_bf, 256, wp_bf, 256, x2_bf, 512, 256,
        gp, bp, mp, vp, x1_bf, 512, nullptr);

    // ---- final: x2 x wf^T + bf -> xo (fp32 in d_out) ----
    mfma_gemm<2><<<512, 256, 0, stream>>>(
        x2_bf, 512, wf_bf, 512, xo, 512, 512,
        nullptr, nullptr, nullptr, nullptr, nullptr, 0, bf_);

    // ---- L2 normalize xo in place + bf16 copy ----
    l2norm_rows<<<4096, 256, 0, stream>>>(xo, xn_bf);

    // ---- sims + max over protos -> act (XCD-remapped 1D grid) ----
    sims_mfma<<<1280, 256, 0, stream>>>(xn_bf, prot_bf, act);

    // ---- logits ----
    logits_max<<<320, 256, 0, stream>>>(act, lsc, logits);
}

// Round 16
// 188.175 us; speedup vs baseline: 1.0161x; 1.0017x over previous
//
#include <hip/hip_runtime.h>
#include <math.h>

#define BN_EPS 1e-5f

typedef __attribute__((ext_vector_type(8))) short short8v;   // 8 x bf16 bits
typedef __attribute__((ext_vector_type(8))) unsigned short ushort8v;
typedef __attribute__((ext_vector_type(4))) float f32x4;

__device__ __forceinline__ unsigned short f2b(float f) {
    unsigned int u = __float_as_uint(f);
    return (unsigned short)((u + 0x7FFFu + ((u >> 16) & 1u)) >> 16);
}
__device__ __forceinline__ float b2f(unsigned short h) {
    return __uint_as_float(((unsigned int)h) << 16);
}

typedef __attribute__((address_space(1))) const unsigned int gas_uint;
typedef __attribute__((address_space(3))) unsigned int las_uint;
__device__ __forceinline__ void gload16(const void* g, void* l) {
    __builtin_amdgcn_global_load_lds((gas_uint*)g, (las_uint*)l, 16, 0, 0);
}

#define VMCNT2()  asm volatile("s_waitcnt vmcnt(2)"  ::: "memory")
#define VMCNT3()  asm volatile("s_waitcnt vmcnt(3)"  ::: "memory")
#define VMCNT4()  asm volatile("s_waitcnt vmcnt(4)"  ::: "memory")
#define VMCNT6()  asm volatile("s_waitcnt vmcnt(6)"  ::: "memory")
#define VMCNT0()  asm volatile("s_waitcnt vmcnt(0)"  ::: "memory")
#define LGKM0()   asm volatile("s_waitcnt lgkmcnt(0)" ::: "memory")
#define SBAR()    __builtin_amdgcn_s_barrier()
#define SCHED0()  __builtin_amdgcn_sched_barrier(0)

// ---------------------------------------------------------------------------
// prep_all: weight/proto conversions + conv transpose + opad zero.
// ---------------------------------------------------------------------------
__global__ __launch_bounds__(256) void prep_all(
    const float* __restrict__ w0,  const float* __restrict__ wr,
    const float* __restrict__ wp,  const float* __restrict__ wf,
    const float* __restrict__ prot,
    const float* __restrict__ wl,  const float* __restrict__ wg,
    unsigned short* __restrict__ w0_o, unsigned short* __restrict__ wr_o,
    unsigned short* __restrict__ wp_o, unsigned short* __restrict__ wf_o,
    unsigned short* __restrict__ prot_o,
    unsigned short* __restrict__ wt_o, unsigned short* __restrict__ opad)
{
    int i = blockIdx.x * 256 + threadIdx.x;
    if (i >= 557056) return;
    if (i >= 225280) {                // zero opad
        ushort8v z;
#pragma unroll
        for (int k = 0; k < 8; ++k) z[k] = 0;
        *(ushort8v*)(opad + (size_t)(i - 225280) * 8) = z;
        return;
    }
    if (i >= 188416) {                // conv weight transpose (gather)
        int e0 = (i - 188416) * 8;
        ushort8v u;
#pragma unroll
        for (int q = 0; q < 8; ++q) {
            int e = e0 + q;
            int br = e >= 147456;
            int j  = e - br * 147456;
            int tap = j >> 14, oc = (j >> 7) & 127, ic = j & 127;
            const float* src = br ? wg : wl;
            u[q] = f2b(src[((oc << 7) + ic) * 9 + tap]);
        }
        *(ushort8v*)(wt_o + (size_t)e0) = u;
        return;
    }
    const float* src; unsigned short* dst; int off;
    if      (i <  49152) { src = w0;   dst = w0_o;   off = i; }
    else if (i <  57344) { src = wr;   dst = wr_o;   off = i - 49152; }
    else if (i <  73728) { src = wp;   dst = wp_o;   off = i - 57344; }
    else if (i < 106496) { src = wf;   dst = wf_o;   off = i - 73728; }
    else                 { src = prot; dst = prot_o; off = i - 106496; }
    const float4* p = (const float4*)(src + (size_t)off * 8);
    float4 a = p[0], b = p[1];
    ushort8v r;
    r[0] = f2b(a.x); r[1] = f2b(a.y); r[2] = f2b(a.z); r[3] = f2b(a.w);
    r[4] = f2b(b.x); r[5] = f2b(b.y); r[6] = f2b(b.z); r[7] = f2b(b.w);
    *(ushort8v*)(dst + (size_t)off * 8) = r;
}

// ---------------------------------------------------------------------------
// Adapter GEMM (R13-exact: 2D linear grid — sequential HBM A-stream; the
// XCD remap measurably HURT this kernel, R15): fp32 A converted in-kernel,
// depth-1. Tile 128x128, BK=32, 4 waves, acc 4x4.
// ---------------------------------------------------------------------------
__global__ __launch_bounds__(256, 3) void mfma_gemm_f32a(
    const float* __restrict__ A, int lda,
    const unsigned short* __restrict__ Wt, int ldw,
    unsigned short* __restrict__ outp, int ldc, int Kdim,
    const float* __restrict__ bng, const float* __restrict__ bnb,
    const float* __restrict__ bnm, const float* __restrict__ bnv)
{
    __shared__ short8v Asta[2][512];
    __shared__ short8v Bsta[2][512];
    const int t  = threadIdx.x;
    const int l  = t & 63, wv = t >> 6;
    const int wm = wv >> 1, wn = wv & 1;
    const int m0 = blockIdx.x << 7, n0 = blockIdx.y << 7;

    const int r0  = t & 127;
    const int kb0 = t >> 7;

    const float*          Apf = A  + (size_t)(m0 + r0) * lda + kb0 * 8;
    const unsigned short* Bp  = Wt + (size_t)(n0 + r0) * ldw + kb0 * 8;

    f32x4 acc[4][4];
#pragma unroll
    for (int mf = 0; mf < 4; ++mf)
#pragma unroll
        for (int nf = 0; nf < 4; ++nf)
#pragma unroll
            for (int j = 0; j < 4; ++j) acc[mf][nf][j] = 0.f;

    const int arow = wm * 64 + (l & 15);
    const int brow = wn * 64 + (l & 15);
    const int kq   = l >> 4;
    const int nK   = Kdim >> 5;

    float4 areg[2][2];

#define LOADA(k0)                                                   \
    do {                                                            \
        areg[0][0] = *(const float4*)(Apf + (k0));                  \
        areg[0][1] = *(const float4*)(Apf + (k0) + 4);              \
        areg[1][0] = *(const float4*)(Apf + (k0) + 16);             \
        areg[1][1] = *(const float4*)(Apf + (k0) + 20);             \
    } while (0)

#define WRITEA(buf)                                                 \
    do {                                                            \
        _Pragma("unroll")                                           \
        for (int c_ = 0; c_ < 2; ++c_) {                            \
            ushort8v u_;                                            \
            u_[0] = f2b(areg[c_][0].x); u_[1] = f2b(areg[c_][0].y); \
            u_[2] = f2b(areg[c_][0].z); u_[3] = f2b(areg[c_][0].w); \
            u_[4] = f2b(areg[c_][1].x); u_[5] = f2b(areg[c_][1].y); \
            u_[6] = f2b(areg[c_][1].z); u_[7] = f2b(areg[c_][1].w); \
            *(ushort8v*)&Asta[buf][t + 256 * c_] = u_;              \
        }                                                           \
    } while (0)

#define STAGEB(buf, k0)                                      \
    do {                                                     \
        gload16(Bp + (k0),      &Bsta[buf][wv * 64]);        \
        gload16(Bp + (k0) + 16, &Bsta[buf][wv * 64 + 256]);  \
    } while (0)

    LOADA(0);
    STAGEB(0, 0);
    VMCNT2();
    WRITEA(0);
    VMCNT0(); LGKM0();
    SBAR();

    int cur = 0;
    for (int ks = 0; ks < nK; ++ks) {
        const bool more = (ks + 1 < nK);
        if (more) {
            LOADA((ks + 1) << 5);
            STAGEB(cur ^ 1, (ks + 1) << 5);
        }
        short8v af[4], bfv[4];
#pragma unroll
        for (int mf = 0; mf < 4; ++mf) af[mf]  = Asta[cur][kq * 128 + arow + mf * 16];
#pragma unroll
        for (int nf = 0; nf < 4; ++nf) bfv[nf] = Bsta[cur][kq * 128 + brow + nf * 16];
#pragma unroll
        for (int mf = 0; mf < 4; ++mf)
#pragma unroll
            for (int nf = 0; nf < 4; ++nf)
                acc[mf][nf] = __builtin_amdgcn_mfma_f32_16x16x32_bf16(
                    af[mf], bfv[nf], acc[mf][nf], 0, 0, 0);
        if (more) {
            VMCNT2();
            WRITEA(cur ^ 1);
        }
        LGKM0(); SCHED0();
        VMCNT0();
        SBAR();
        cur ^= 1;
    }
#undef LOADA
#undef WRITEA
#undef STAGEB

    float s[4], sh[4];
    int cols[4];
#pragma unroll
    for (int nf = 0; nf < 4; ++nf) {
        int col = n0 + wn * 64 + nf * 16 + (l & 15);
        cols[nf] = col;
        float sc = bng[col] * rsqrtf(bnv[col] + BN_EPS);
        s[nf]  = sc;
        sh[nf] = bnb[col] - bnm[col] * sc;
    }
#pragma unroll
    for (int mf = 0; mf < 4; ++mf) {
#pragma unroll
        for (int j = 0; j < 4; ++j) {
            int row = m0 + wm * 64 + mf * 16 + kq * 4 + j;
#pragma unroll
            for (int nf = 0; nf < 4; ++nf) {
                float v2 = fmaxf(acc[mf][nf][j] * s[nf] + sh[nf], 0.f);
                outp[(size_t)row * ldc + cols[nf]] = f2b(v2);
            }
        }
    }
}

// ---------------------------------------------------------------------------
// bf16 MFMA NT GEMM (R6-proven + XCD remap, kept from R15): tile 128x128,
// BK=32, 4 waves, acc 4x4, 2-buffer LDS + counted vmcnt(4). 1D grid 512.
// EPI 1: BN+res+ReLU->bf16  2: +bias->fp32
// ---------------------------------------------------------------------------
template <int EPI>
__global__ __launch_bounds__(256, 3) void mfma_gemm(
    const unsigned short* __restrict__ A, int lda,
    const unsigned short* __restrict__ Wt, int ldw,
    void* __restrict__ outp, int ldc, int Kdim,
    const float* __restrict__ bng, const float* __restrict__ bnb,
    const float* __restrict__ bnm, const float* __restrict__ bnv,
    const unsigned short* __restrict__ res, int ldres,
    const float* __restrict__ bias)
{
    __shared__ short8v Asta[2][512];
    __shared__ short8v Bsta[2][512];
    const int t  = threadIdx.x;
    const int l  = t & 63, wv = t >> 6;
    const int wm = wv >> 1, wn = wv & 1;

    const int bid = blockIdx.x;           // 0..511
    const int xcd = bid & 7, v = bid >> 3;
    const int m0 = (xcd * 16 + (v >> 2)) << 7;
    const int n0 = (v & 3) << 7;

    const int r0  = t & 127;
    const int kb0 = t >> 7;

    const unsigned short* Ap = A  + (size_t)(m0 + r0) * lda + kb0 * 8;
    const unsigned short* Bp = Wt + (size_t)(n0 + r0) * ldw + kb0 * 8;

    f32x4 acc[4][4];
#pragma unroll
    for (int mf = 0; mf < 4; ++mf)
#pragma unroll
        for (int nf = 0; nf < 4; ++nf)
#pragma unroll
            for (int j = 0; j < 4; ++j) acc[mf][nf][j] = 0.f;

    const int arow = wm * 64 + (l & 15);
    const int brow = wn * 64 + (l & 15);
    const int kq   = l >> 4;
    const int nK   = Kdim >> 5;

#define STAGE_G(buf, k0)                                     \
    do {                                                     \
        gload16(Ap + (k0),      &Asta[buf][wv * 64]);        \
        gload16(Ap + (k0) + 16, &Asta[buf][wv * 64 + 256]);  \
        gload16(Bp + (k0),      &Bsta[buf][wv * 64]);        \
        gload16(Bp + (k0) + 16, &Bsta[buf][wv * 64 + 256]);  \
    } while (0)

    STAGE_G(0, 0);
    int cur = 0;
    for (int ks = 0; ks < nK; ++ks) {
        if (ks + 1 < nK) { STAGE_G(cur ^ 1, (ks + 1) << 5); VMCNT4(); }
        else             { VMCNT0(); }
        SBAR();
        short8v af[4], bfv[4];
#pragma unroll
        for (int mf = 0; mf < 4; ++mf) af[mf]  = Asta[cur][kq * 128 + arow + mf * 16];
#pragma unroll
        for (int nf = 0; nf < 4; ++nf) bfv[nf] = Bsta[cur][kq * 128 + brow + nf * 16];
#pragma unroll
        for (int mf = 0; mf < 4; ++mf)
#pragma unroll
            for (int nf = 0; nf < 4; ++nf)
                acc[mf][nf] = __builtin_amdgcn_mfma_f32_16x16x32_bf16(
                    af[mf], bfv[nf], acc[mf][nf], 0, 0, 0);
        LGKM0(); SCHED0();
        SBAR();
        cur ^= 1;
    }
#undef STAGE_G

    float s[4], sh[4];
    int cols[4];
#pragma unroll
    for (int nf = 0; nf < 4; ++nf) {
        int col = n0 + wn * 64 + nf * 16 + (l & 15);
        cols[nf] = col;
        if (EPI == 2) { s[nf] = 1.f; sh[nf] = bias[col]; }
        else {
            float sc = bng[col] * rsqrtf(bnv[col] + BN_EPS);
            s[nf]  = sc;
            sh[nf] = bnb[col] - bnm[col] * sc;
        }
    }
#pragma unroll
    for (int mf = 0; mf < 4; ++mf) {
#pragma unroll
        for (int j = 0; j < 4; ++j) {
            int row = m0 + wm * 64 + mf * 16 + kq * 4 + j;
#pragma unroll
            for (int nf = 0; nf < 4; ++nf) {
                float v2 = acc[mf][nf][j] * s[nf] + sh[nf];
                if (EPI == 1) v2 += b2f(res[(size_t)row * ldres + cols[nf]]);
                if (EPI != 2) v2 = fmaxf(v2, 0.f);
                if (EPI == 2) {
                    ((float*)outp)[(size_t)row * ldc + cols[nf]] = v2;
                } else {
                    ((unsigned short*)outp)[(size_t)row * ldc + cols[nf]] = f2b(v2);
                }
            }
        }
    }
}

// ---------------------------------------------------------------------------
// reduce GEMM, BM=64 (grid 256 blocks): unchanged.
// ---------------------------------------------------------------------------
__global__ __launch_bounds__(256, 3) void mfma_gemm64_pad(
    const unsigned short* __restrict__ A,
    const unsigned short* __restrict__ Wt,
    unsigned short* __restrict__ opad,
    const float* __restrict__ bng, const float* __restrict__ bnb,
    const float* __restrict__ bnm, const float* __restrict__ bnv)
{
    __shared__ short8v Asta[2][256];
    __shared__ short8v Bsta[2][512];
    const int t  = threadIdx.x;
    const int l  = t & 63, wv = t >> 6;
    const int wm = wv >> 1, wn = wv & 1;
    const int m0 = blockIdx.x << 6;

    const unsigned short* Ap = A  + (size_t)(m0 + (t & 63)) * 512 + (t >> 6) * 8;
    const unsigned short* Bp = Wt + (size_t)(t & 127) * 512 + (t >> 7) * 8;

    f32x4 acc[2][4];
#pragma unroll
    for (int mf = 0; mf < 2; ++mf)
#pragma unroll
        for (int nf = 0; nf < 4; ++nf)
#pragma unroll
            for (int j = 0; j < 4; ++j) acc[mf][nf][j] = 0.f;

    const int arow = wm * 32 + (l & 15);
    const int brow = wn * 64 + (l & 15);
    const int kq   = l >> 4;

#define STAGE_R(buf, k0)                                     \
    do {                                                     \
        gload16(Ap + (k0),      &Asta[buf][wv * 64]);        \
        gload16(Bp + (k0),      &Bsta[buf][wv * 64]);        \
        gload16(Bp + (k0) + 16, &Bsta[buf][wv * 64 + 256]);  \
    } while (0)

    STAGE_R(0, 0);
    int cur = 0;
    for (int ks = 0; ks < 16; ++ks) {
        if (ks + 1 < 16) { STAGE_R(cur ^ 1, (ks + 1) << 5); VMCNT3(); }
        else             { VMCNT0(); }
        SBAR();
        short8v af[2], bfv[4];
#pragma unroll
        for (int mf = 0; mf < 2; ++mf) af[mf]  = Asta[cur][kq * 64 + arow + mf * 16];
#pragma unroll
        for (int nf = 0; nf < 4; ++nf) bfv[nf] = Bsta[cur][kq * 128 + brow + nf * 16];
#pragma unroll
        for (int mf = 0; mf < 2; ++mf)
#pragma unroll
            for (int nf = 0; nf < 4; ++nf)
                acc[mf][nf] = __builtin_amdgcn_mfma_f32_16x16x32_bf16(
                    af[mf], bfv[nf], acc[mf][nf], 0, 0, 0);
        LGKM0(); SCHED0();
        SBAR();
        cur ^= 1;
    }
#undef STAGE_R

    float s[4], sh[4];
    int cols[4];
#pragma unroll
    for (int nf = 0; nf < 4; ++nf) {
        int col = wn * 64 + nf * 16 + (l & 15);
        cols[nf] = col;
        float sc = bng[col] * rsqrtf(bnv[col] + BN_EPS);
        s[nf]  = sc;
        sh[nf] = bnb[col] - bnm[col] * sc;
    }
#pragma unroll
    for (int mf = 0; mf < 2; ++mf) {
#pragma unroll
        for (int j = 0; j < 4; ++j) {
            int row = m0 + wm * 32 + mf * 16 + kq * 4 + j;
            int b = row >> 10, h = (row >> 5) & 31, ww = row & 31;
            size_t pbase = ((size_t)(b * 36 + h + 2) * 36 + (ww + 2)) * 128;
#pragma unroll
            for (int nf = 0; nf < 4; ++nf) {
                float v2 = fmaxf(acc[mf][nf][j] * s[nf] + sh[nf], 0.f);
                opad[pbase + cols[nf]] = f2b(v2);
            }
        }
    }
}

// ---------------------------------------------------------------------------
// Both 3x3 convs (R6-proven + XCD remap on x, kept from R15).
// grid (256, 2): y = branch (dil = 1+y).
// ---------------------------------------------------------------------------
__global__ __launch_bounds__(256, 3) void conv_mfma(
    const unsigned short* __restrict__ opad,
    const unsigned short* __restrict__ wt_all,
    const float* __restrict__ g1, const float* __restrict__ b1,
    const float* __restrict__ m1, const float* __restrict__ v1,
    const float* __restrict__ g2, const float* __restrict__ b2,
    const float* __restrict__ m2, const float* __restrict__ v2,
    unsigned short* __restrict__ lg)
{
    __shared__ short8v Asta[2][512];
    __shared__ short8v Bsta[2][1024];
    const int t = threadIdx.x;
    const int l = t & 63, wv = t >> 6;
    const int wm = wv >> 1, wn = wv & 1;

    const int mbo = blockIdx.x;            // 0..255
    const int m0  = ((mbo & 7) * 32 + (mbo >> 3)) << 6;

    const int br = blockIdx.y;
    const int dil = 1 + br;
    const unsigned short* wtb = wt_all + (size_t)br * 147456;

    const int r0 = t & 63;
    const int m  = m0 + r0;
    const int bb = m >> 10, h = (m >> 5) & 31, wc = m & 31;
    const ptrdiff_t pbase = ((ptrdiff_t)(bb * 36 + h + 2) * 36 + (wc + 2)) * 128;
    const unsigned short* ApT = opad + pbase + (t >> 6) * 8;
    const unsigned short* BpT = wtb + (size_t)(t & 127) * 128 + (t >> 7) * 8;

    f32x4 acc[2][4];
#pragma unroll
    for (int mf = 0; mf < 2; ++mf)
#pragma unroll
        for (int nf = 0; nf < 4; ++nf)
#pragma unroll
            for (int j = 0; j < 4; ++j) acc[mf][nf][j] = 0.f;

    const int arow = wm * 32 + (l & 15);
    const int bcol = wn * 64 + (l & 15);
    const int kq   = l >> 4;

#define STAGE_C(buf, s)                                                        \
    do {                                                                       \
        int tap_ = (s) >> 1, hh_ = ((s) & 1) * 64;                             \
        int dh_ = tap_ / 3 - 1, dw_ = tap_ % 3 - 1;                            \
        const unsigned short* Ap_ = ApT + (ptrdiff_t)((dh_ * 36 + dw_) * dil) * 128 + hh_; \
        const unsigned short* Bp_ = BpT + (size_t)tap_ * 16384 + hh_;          \
        gload16(Ap_,      &Asta[buf][wv * 64]);                                \
        gload16(Ap_ + 32, &Asta[buf][wv * 64 + 256]);                          \
        gload16(Bp_,      &Bsta[buf][wv * 64]);                                \
        gload16(Bp_ + 16, &Bsta[buf][wv * 64 + 256]);                          \
        gload16(Bp_ + 32, &Bsta[buf][wv * 64 + 512]);                          \
        gload16(Bp_ + 48, &Bsta[buf][wv * 64 + 768]);                          \
    } while (0)

    STAGE_C(0, 0);
    int cur = 0;
    for (int s = 0; s < 18; ++s) {
        if (s + 1 < 18) { STAGE_C(cur ^ 1, s + 1); VMCNT6(); }
        else            { VMCNT0(); }
        SBAR();
        short8v af[2][2], bfv[2][4];
#pragma unroll
        for (int kk = 0; kk < 2; ++kk) {
            int kb = kk * 4 + kq;
            af[kk][0] = Asta[cur][kb * 64 + arow];
            af[kk][1] = Asta[cur][kb * 64 + arow + 16];
#pragma unroll
            for (int nf = 0; nf < 4; ++nf)
                bfv[kk][nf] = Bsta[cur][kb * 128 + bcol + nf * 16];
        }
#pragma unroll
        for (int kk = 0; kk < 2; ++kk)
#pragma unroll
            for (int mf = 0; mf < 2; ++mf)
#pragma unroll
                for (int nf = 0; nf < 4; ++nf)
                    acc[mf][nf] = __builtin_amdgcn_mfma_f32_16x16x32_bf16(
                        af[kk][mf], bfv[kk][nf], acc[mf][nf], 0, 0, 0);
        LGKM0(); SCHED0();
        SBAR();
        cur ^= 1;
    }
#undef STAGE_C

    const float* gg = br ? g2 : g1;
    const float* gb = br ? b2 : b1;
    const float* gm = br ? m2 : m1;
    const float* gv = br ? v2 : v1;
    float s4[4], sh[4];
    int cols[4];
#pragma unroll
    for (int nf = 0; nf < 4; ++nf) {
        int col = bcol + nf * 16;
        cols[nf] = col;
        float sc = gg[col] * rsqrtf(gv[col] + BN_EPS);
        s4[nf] = sc;
        sh[nf] = gb[col] - gm[col] * sc;
    }
#pragma unroll
    for (int mf = 0; mf < 2; ++mf) {
#pragma unroll
        for (int j = 0; j < 4; ++j) {
            int row = m0 + wm * 32 + mf * 16 + kq * 4 + j;
#pragma unroll
            for (int nf = 0; nf < 4; ++nf) {
                float v2 = fmaxf(acc[mf][nf][j] * s4[nf] + sh[nf], 0.f);
                lg[(size_t)row * 256 + br * 128 + cols[nf]] = f2b(v2);
            }
        }
    }
}

// ---------------------------------------------------------------------------
__global__ __launch_bounds__(256) void l2norm_rows(
    float* __restrict__ x, unsigned short* __restrict__ xn)
{
    const int t    = threadIdx.x;
    const int wv   = t >> 6, lane = t & 63;
    const int row  = (blockIdx.x << 2) + wv;
    float* p = x + (size_t)row * 512 + (lane << 3);
    float4 a = *(float4*)p;
    float4 b = *(float4*)(p + 4);
    float ss = a.x * a.x + a.y * a.y + a.z * a.z + a.w * a.w +
               b.x * b.x + b.y * b.y + b.z * b.z + b.w * b.w;
#pragma unroll
    for (int off = 32; off >= 1; off >>= 1) ss += __shfl_xor(ss, off);
    float sc = 1.f / fmaxf(sqrtf(ss), 1e-12f);
    a.x *= sc; a.y *= sc; a.z *= sc; a.w *= sc;
    b.x *= sc; b.y *= sc; b.z *= sc; b.w *= sc;
    *(float4*)p       = a;
    *(float4*)(p + 4) = b;
    ushort8v r;
    r[0] = f2b(a.x); r[1] = f2b(a.y); r[2] = f2b(a.z); r[3] = f2b(a.w);
    r[4] = f2b(b.x); r[5] = f2b(b.y); r[6] = f2b(b.z); r[7] = f2b(b.w);
    *(ushort8v*)(xn + (size_t)row * 512 + (lane << 3)) = r;
}

// ---------------------------------------------------------------------------
// sims + per-class max (R5 loop + XCD remap, kept from R15): 1D grid 1280.
// ---------------------------------------------------------------------------
__global__ __launch_bounds__(256, 3) void sims_mfma(
    const unsigned short* __restrict__ xn,
    const unsigned short* __restrict__ protos,
    float* __restrict__ act)
{
    __shared__ short8v Asta[2][512];
    __shared__ short8v Bsta[2][512];
    const int t = threadIdx.x;
    const int l = t & 63, wv = t >> 6;
    const int wm = wv >> 1, wn = wv & 1;

    const int bid = blockIdx.x;            // 0..1279
    const int xcd = bid & 7, v = bid >> 3;  // v: 0..159
    const int mb  = xcd * 16 + v / 10;
    const int cp  = v % 10;
    const int m0  = mb << 7;

    const int r0  = t & 127, kb0 = t >> 7;
    const unsigned short* Ap = xn + (size_t)(m0 + r0) * 512 + kb0 * 8;
    const unsigned short* Bp = protos + ((size_t)cp * 128 + r0) * 512 + kb0 * 8;

    f32x4 acc[4][4];
#pragma unroll
    for (int mf = 0; mf < 4; ++mf)
#pragma unroll
        for (int nf = 0; nf < 4; ++nf)
#pragma unroll
            for (int j = 0; j < 4; ++j) acc[mf][nf][j] = 0.f;

    const int arow = wm * 64 + (l & 15);
    const int brow = wn * 64 + (l & 15);
    const int kq   = l >> 4;

#define STAGE_S(buf, k0)                                     \
    do {                                                     \
        gload16(Ap + (k0),      &Asta[buf][wv * 64]);        \
        gload16(Ap + (k0) + 16, &Asta[buf][wv * 64 + 256]);  \
        gload16(Bp + (k0),      &Bsta[buf][wv * 64]);        \
        gload16(Bp + (k0) + 16, &Bsta[buf][wv * 64 + 256]);  \
    } while (0)

    STAGE_S(0, 0);
    __syncthreads();
    int cur = 0;
    for (int ks = 0; ks < 16; ++ks) {
        short8v af[4], bfv[4];
#pragma unroll
        for (int mf = 0; mf < 4; ++mf) af[mf]  = Asta[cur][kq * 128 + arow + mf * 16];
#pragma unroll
        for (int nf = 0; nf < 4; ++nf) bfv[nf] = Bsta[cur][kq * 128 + brow + nf * 16];
        if (ks + 1 < 16) STAGE_S(cur ^ 1, (ks + 1) << 5);
#pragma unroll
        for (int mf = 0; mf < 4; ++mf)
#pragma unroll
            for (int nf = 0; nf < 4; ++nf)
                acc[mf][nf] = __builtin_amdgcn_mfma_f32_16x16x32_bf16(
                    af[mf], bfv[nf], acc[mf][nf], 0, 0, 0);
        __syncthreads();
        cur ^= 1;
    }
#undef STAGE_S

    const int c = (cp << 1) + wn;  // this wave's class
#pragma unroll
    for (int mf = 0; mf < 4; ++mf) {
        float vj[4];
#pragma unroll
        for (int j = 0; j < 4; ++j) {
            float vx = fmaxf(fmaxf(acc[mf][0][j], acc[mf][1][j]),
                             fmaxf(acc[mf][2][j], acc[mf][3][j]));
            vx = fmaxf(vx, __shfl_xor(vx, 1));
            vx = fmaxf(vx, __shfl_xor(vx, 2));
            vx = fmaxf(vx, __shfl_xor(vx, 4));
            vx = fmaxf(vx, __shfl_xor(vx, 8));
            vj[j] = vx;
        }
        if ((l & 15) == 0) {
            int rowb = m0 + wm * 64 + mf * 16 + kq * 4;
#pragma unroll
            for (int j = 0; j < 4; ++j) {
                int row = rowb + j;
                int bb = row >> 10, n = row & 1023;
                act[(((size_t)(bb * 20 + c)) << 10) + n] = vj[j];
            }
        }
    }
}

// ---------------------------------------------------------------------------
__global__ __launch_bounds__(256) void logits_max(
    const float* __restrict__ act, const float* __restrict__ lsc,
    float* __restrict__ logits)
{
    const int bc = blockIdx.x;
    const int t  = threadIdx.x;
    float4 v = *(const float4*)(act + ((size_t)bc << 10) + (t << 2));
    float mx = fmaxf(fmaxf(v.x, v.y), fmaxf(v.z, v.w));
#pragma unroll
    for (int off = 32; off >= 1; off >>= 1) mx = fmaxf(mx, __shfl_xor(mx, off));
    __shared__ float wmred[4];
    if ((t & 63) == 0) wmred[t >> 6] = mx;
    __syncthreads();
    if (t == 0) {
        float m2 = fmaxf(fmaxf(wmred[0], wmred[1]), fmaxf(wmred[2], wmred[3]));
        logits[bc] = m2 * lsc[0];
    }
}

// ---------------------------------------------------------------------------
extern "C" void kernel_launch(void* const* d_in, const int* in_sizes, int n_in,
                              void* d_out, int out_size, void* d_ws, size_t ws_size,
                              hipStream_t stream)
{
    const float* pf   = (const float*)d_in[0];
    const float* prot = (const float*)d_in[1];
    const float* w0   = (const float*)d_in[2];
    const float* g0   = (const float*)d_in[3];
    const float* b0   = (const float*)d_in[4];
    const float* m0v  = (const float*)d_in[5];
    const float* v0   = (const float*)d_in[6];
    const float* wr   = (const float*)d_in[7];
    const float* gr   = (const float*)d_in[8];
    const float* br   = (const float*)d_in[9];
    const float* mr   = (const float*)d_in[10];
    const float* vr   = (const float*)d_in[11];
    const float* wl   = (const float*)d_in[12];
    const float* gl   = (const float*)d_in[13];
    const float* bl   = (const float*)d_in[14];
    const float* ml   = (const float*)d_in[15];
    const float* vl   = (const float*)d_in[16];
    const float* wg   = (const float*)d_in[17];
    const float* gG   = (const float*)d_in[18];
    const float* bG   = (const float*)d_in[19];
    const float* mG   = (const float*)d_in[20];
    const float* vG   = (const float*)d_in[21];
    const float* wp   = (const float*)d_in[22];
    const float* gp   = (const float*)d_in[23];
    const float* bp   = (const float*)d_in[24];
    const float* mp   = (const float*)d_in[25];
    const float* vp   = (const float*)d_in[26];
    const float* wf   = (const float*)d_in[27];
    const float* bf_  = (const float*)d_in[28];
    const float* lsc  = (const float*)d_in[29];

    char* ws = (char*)d_ws;
    unsigned short* w0_bf    = (unsigned short*)(ws);             // 786432 B
    unsigned short* wr_bf    = (unsigned short*)(ws + 786432);    // 131072
    unsigned short* wt_bf    = (unsigned short*)(ws + 917504);    // 589824
    unsigned short* wp_bf    = (unsigned short*)(ws + 1507328);   // 262144
    unsigned short* wf_bf    = (unsigned short*)(ws + 1769472);   // 524288
    unsigned short* prot_bf  = (unsigned short*)(ws + 2293760);   // 1310720
    unsigned short* x1_bf    = (unsigned short*)(ws + 3604480);   // 16777216
    unsigned short* opad     = (unsigned short*)(ws + 20381696);  // 5308416
    unsigned short* lg_bf    = (unsigned short*)(ws + 25690112);  // 8388608
    unsigned short* x2_bf    = (unsigned short*)(ws + 34078720);  // 16777216
    unsigned short* xn_bf    = (unsigned short*)(ws + 50855936);  // 16777216

    float* out    = (float*)d_out;
    float* logits = out;            // [16][20]
    float* act    = out + 320;      // [16][20][1024]
    float* xo     = out + 328000;   // [16384][512] fp32

    // ---- weight/proto conversions + conv transpose + opad zero ----
    prep_all<<<2176, 256, 0, stream>>>(
        w0, wr, wp, wf, prot, wl, wg,
        w0_bf, wr_bf, wp_bf, wf_bf, prot_bf, wt_bf, opad);

    // ---- adapter: fp32 pf x w0^T -> BN -> ReLU -> x1 (bf16), linear grid ----
    mfma_gemm_f32a<<<dim3(128, 4), 256, 0, stream>>>(
        pf, 768, w0_bf, 768, x1_bf, 512, 768, g0, b0, m0v, v0);

    // ---- reduce: x1 x wr^T -> BN -> ReLU -> opad (BM=64, 256 blocks) ----
    mfma_gemm64_pad<<<256, 256, 0, stream>>>(
        x1_bf, wr_bf, opad, gr, br, mr, vr);

    // ---- both 3x3 conv branches -> lg (bf16 [16384][256]) ----
    conv_mfma<<<dim3(256, 2), 256, 0, stream>>>(
        opad, wt_bf, gl, bl, ml, vl, gG, bG, mG, vG, lg_bf);

    // ---- project: lg x wp^T -> BN -> +x1 -> ReLU -> x2 (bf16) ----
    mfma_gemm<1><<<512, 256, 0, stream>>>(
        lg_bf, 256, wp_bf, 256, x2_bf, 512, 256,
        gp, bp, mp, vp, x1_bf, 512, nullptr);

    // ---- final: x2 x wf^T + bf -> xo (fp32 in d_out) ----
    mfma_gemm<2><<<512, 256, 0, stream>>>(
        x2_bf, 512, wf_bf, 512, xo, 512, 512,
        nullptr, nullptr, nullptr, nullptr, nullptr, 0, bf_);

    // ---- L2 normalize xo in place + bf16 copy ----
    l2norm_rows<<<4096, 256, 0, stream>>>(xo, xn_bf);

    // ---- sims + max over protos -> act (XCD-remapped 1D grid) ----
    sims_mfma<<<1280, 256, 0, stream>>>(xn_bf, prot_bf, act);

    // ---- logits ----
    logits_max<<<320, 256, 0, stream>>>(act, lsc, logits);
}